// Round 1
// baseline (873.898 us; speedup 1.0000x reference)
//
#include <hip/hip_runtime.h>
#include <math.h>

// Problem constants (B=32, T=128, K=16, L=16)
//   N = B*T = 4096 tokens, 784 pixels, hidden 400.
// Pipeline:
//   K1 enc1 : h[4096,400]   = relu(y @ W1^T + b1)
//   K2 enc2z: ml[4096,32]   = h @ W2^T + b2 ; z = mu + eps*exp(0.5*logvar)
//   K3 base : base[4096,400]= z @ Wz^T + dec_fc_b
//   K4 dec  : lb[4096,16]   : for each k: hk=relu(base+Wx_k); logits=hk@decW^T+db;
//                             lb[n,k] = -sum_o bce(logit,y)/100   (fused, y_rec never stored)
//   K5 hmm  : scaled linear-domain forward/backward -> gamma, xi (normalized => scales cancel)

// ---------------- K1: h = relu(y @ W1^T + b1) ----------------
// 64x64 tile, 4x4 micro, K-tile 16 (784 = 49*16 exact)
__global__ __launch_bounds__(256, 4)
void k_enc1(const float* __restrict__ y, const float* __restrict__ w1,
            const float* __restrict__ b1, float* __restrict__ hout) {
  __shared__ __align__(16) float a_lds[16 * 68];
  __shared__ __align__(16) float b_lds[16 * 68];
  const int tid = threadIdx.x;
  const int n0 = blockIdx.x * 64;
  const int i0 = blockIdx.y * 64;
  const int tm = tid & 15, ti = tid >> 4;
  const int lm = tid >> 2;          // load row 0..63
  const int lk = (tid & 3) << 2;    // k offset (f4)
  const int irow = i0 + lm;
  float acc[4][4];
#pragma unroll
  for (int r = 0; r < 4; ++r)
#pragma unroll
    for (int c = 0; c < 4; ++c) acc[r][c] = 0.f;

  for (int k0 = 0; k0 < 784; k0 += 16) {
    __syncthreads();
    float4 av = *(const float4*)&y[(n0 + lm) * 784 + k0 + lk];
    float4 bv = make_float4(0.f, 0.f, 0.f, 0.f);
    if (irow < 400) bv = *(const float4*)&w1[irow * 784 + k0 + lk];
    a_lds[(lk + 0) * 68 + lm] = av.x;
    a_lds[(lk + 1) * 68 + lm] = av.y;
    a_lds[(lk + 2) * 68 + lm] = av.z;
    a_lds[(lk + 3) * 68 + lm] = av.w;
    b_lds[(lk + 0) * 68 + lm] = bv.x;
    b_lds[(lk + 1) * 68 + lm] = bv.y;
    b_lds[(lk + 2) * 68 + lm] = bv.z;
    b_lds[(lk + 3) * 68 + lm] = bv.w;
    __syncthreads();
#pragma unroll
    for (int kk = 0; kk < 16; ++kk) {
      float4 a = *(const float4*)&a_lds[kk * 68 + tm * 4];
      float4 b = *(const float4*)&b_lds[kk * 68 + ti * 4];
      float aa[4] = {a.x, a.y, a.z, a.w};
      float bb[4] = {b.x, b.y, b.z, b.w};
#pragma unroll
      for (int r = 0; r < 4; ++r)
#pragma unroll
        for (int c = 0; c < 4; ++c) acc[r][c] = fmaf(aa[r], bb[c], acc[r][c]);
    }
  }
  const int ic = i0 + ti * 4;
  if (ic < 400) {
    float4 bias = *(const float4*)&b1[ic];
    float bb[4] = {bias.x, bias.y, bias.z, bias.w};
#pragma unroll
    for (int r = 0; r < 4; ++r) {
      float4 o;
      o.x = fmaxf(acc[r][0] + bb[0], 0.f);
      o.y = fmaxf(acc[r][1] + bb[1], 0.f);
      o.z = fmaxf(acc[r][2] + bb[2], 0.f);
      o.w = fmaxf(acc[r][3] + bb[3], 0.f);
      *(float4*)&hout[(n0 + tm * 4 + r) * 400 + ic] = o;
    }
  }
}

// ---------------- K2: ml = h @ W2^T + b2, z = mu + eps*exp(0.5*logvar) ----------------
// block = 128 threads, 4 token rows each
__global__ __launch_bounds__(128, 4)
void k_enc2z(const float* __restrict__ h, const float* __restrict__ w2,
             const float* __restrict__ b2, const float* __restrict__ eps,
             float* __restrict__ z) {
  __shared__ __align__(16) float h_lds[4 * 400];
  __shared__ __align__(16) float w2_lds[32 * 404];
  __shared__ float ml_lds[4 * 32];
  const int tid = threadIdx.x;
  const int n0 = blockIdx.x * 4;
  for (int idx = tid; idx < 400; idx += 128) {  // 4 rows * 100 f4
    int r = idx / 100, c = idx % 100;
    *(float4*)&h_lds[r * 400 + c * 4] = *(const float4*)&h[(n0 + r) * 400 + c * 4];
  }
  for (int idx = tid; idx < 3200; idx += 128) {  // 32 rows * 100 f4
    int r = idx / 100, c = idx % 100;
    *(float4*)&w2_lds[r * 404 + c * 4] = *(const float4*)&w2[r * 400 + c * 4];
  }
  __syncthreads();
  const int c_ = tid & 31, n_ = tid >> 5;  // n_ 0..3
  float acc = 0.f;
  for (int q = 0; q < 100; ++q) {
    float4 hv = *(const float4*)&h_lds[n_ * 400 + q * 4];
    float4 wv = *(const float4*)&w2_lds[c_ * 404 + q * 4];
    acc += hv.x * wv.x + hv.y * wv.y + hv.z * wv.z + hv.w * wv.w;
  }
  ml_lds[n_ * 32 + c_] = acc + b2[c_];
  __syncthreads();
  if (tid < 64) {
    int n2 = tid >> 4, l = tid & 15;
    float mu = ml_lds[n2 * 32 + l];
    float lv = ml_lds[n2 * 32 + 16 + l];
    z[(n0 + n2) * 16 + l] = mu + eps[(n0 + n2) * 16 + l] * expf(0.5f * lv);
  }
}

// ---------------- K3: base = z @ Wz^T + dec_fc_b ----------------
__global__ __launch_bounds__(256, 4)
void k_base(const float* __restrict__ z, const float* __restrict__ dfw,
            const float* __restrict__ dfb, float* __restrict__ base) {
  __shared__ float z_lds[16 * 16];
  __shared__ __align__(16) float wz_lds[400 * 20];
  const int tid = threadIdx.x;
  const int n0 = blockIdx.x * 16;
  if (tid < 64) {
    int n = tid >> 2, c = (tid & 3) * 4;
    *(float4*)&z_lds[n * 16 + c] = *(const float4*)&z[(n0 + n) * 16 + c];
  }
  for (int idx = tid; idx < 1600; idx += 256) {  // 400 rows * 4 f4 (first 16 cols)
    int i = idx >> 2, c = (idx & 3) * 4;
    *(float4*)&wz_lds[i * 20 + c] = *(const float4*)&dfw[i * 32 + c];
  }
  __syncthreads();
  for (int idx = tid; idx < 6400; idx += 256) {
    int n = idx / 400, i = idx % 400;
    float acc = dfb[i];
#pragma unroll
    for (int q = 0; q < 4; ++q) {
      float4 zv = *(const float4*)&z_lds[n * 16 + q * 4];
      float4 wv = *(const float4*)&wz_lds[i * 20 + q * 4];
      acc += zv.x * wv.x + zv.y * wv.y + zv.z * wv.z + zv.w * wv.w;
    }
    base[(n0 + n) * 400 + i] = acc;
  }
}

// ---------------- K4: decoder GEMM + fused BCE reduction ----------------
// block: k fixed, 128 token rows. o-tiles of 128, h-chunks of 48.
// wave = 64x64 subtile (8n x 8o micro per lane), acc in regs, transposed LDS [h][n]/[h][o].
#define PW 132
__global__ __launch_bounds__(256, 2)
void k_dec(const float* __restrict__ base, const float* __restrict__ dfw,
           const float* __restrict__ decw, const float* __restrict__ decb,
           const float* __restrict__ y, float* __restrict__ lb) {
  __shared__ __align__(16) float hk_lds[48 * PW];
  __shared__ __align__(16) float w_lds[48 * PW];
  __shared__ float wx_lds[432];
  __shared__ float red[256];
  const int tid = threadIdx.x;
  const int k = blockIdx.y;
  const int n0 = blockIdx.x * 128;
  const int wav = tid >> 6, lane = tid & 63;
  const int wn = wav >> 1, wo = wav & 1;
  const int ttn = lane >> 3, tto = lane & 7;
  const int nbase = wn * 64 + ttn * 8;  // local n of micro tile
  const int obase = wo * 64 + tto * 8;  // local o of micro tile

  for (int i = tid; i < 432; i += 256)
    wx_lds[i] = (i < 400) ? dfw[i * 32 + 16 + k] : 0.f;
  red[tid] = 0.f;
  float pr[8];
#pragma unroll
  for (int i = 0; i < 8; ++i) pr[i] = 0.f;

#pragma unroll 1
  for (int ot = 0; ot < 7; ++ot) {
    const int o0 = ot * 128;
    float acc[8][8];
#pragma unroll
    for (int i = 0; i < 8; ++i)
#pragma unroll
      for (int j = 0; j < 8; ++j) acc[i][j] = 0.f;

#pragma unroll 1
    for (int hc = 0; hc < 9; ++hc) {
      const int h0 = hc * 48;
      __syncthreads();
      // stage hk (transposed [h][n]) : 128 rows * 12 f4
      for (int idx = tid; idx < 1536; idx += 256) {
        int nr = idx / 12, hcf = idx % 12;
        int gh = h0 + hcf * 4;
        float4 v = make_float4(0.f, 0.f, 0.f, 0.f);
        if (gh < 400) {
          float4 bb = *(const float4*)&base[(n0 + nr) * 400 + gh];
          v.x = fmaxf(bb.x + wx_lds[gh + 0], 0.f);
          v.y = fmaxf(bb.y + wx_lds[gh + 1], 0.f);
          v.z = fmaxf(bb.z + wx_lds[gh + 2], 0.f);
          v.w = fmaxf(bb.w + wx_lds[gh + 3], 0.f);
        }
        hk_lds[(hcf * 4 + 0) * PW + nr] = v.x;
        hk_lds[(hcf * 4 + 1) * PW + nr] = v.y;
        hk_lds[(hcf * 4 + 2) * PW + nr] = v.z;
        hk_lds[(hcf * 4 + 3) * PW + nr] = v.w;
      }
      // stage decW (transposed [h][o])
      for (int idx = tid; idx < 1536; idx += 256) {
        int orr = idx / 12, hcf = idx % 12;
        int gh = h0 + hcf * 4;
        float4 v = make_float4(0.f, 0.f, 0.f, 0.f);
        if (gh < 400 && (o0 + orr) < 784)
          v = *(const float4*)&decw[(o0 + orr) * 400 + gh];
        w_lds[(hcf * 4 + 0) * PW + orr] = v.x;
        w_lds[(hcf * 4 + 1) * PW + orr] = v.y;
        w_lds[(hcf * 4 + 2) * PW + orr] = v.z;
        w_lds[(hcf * 4 + 3) * PW + orr] = v.w;
      }
      __syncthreads();
      for (int hh = 0; hh < 48; ++hh) {
        float4 a0 = *(const float4*)&hk_lds[hh * PW + nbase];
        float4 a1 = *(const float4*)&hk_lds[hh * PW + nbase + 4];
        float4 b0 = *(const float4*)&w_lds[hh * PW + obase];
        float4 b1 = *(const float4*)&w_lds[hh * PW + obase + 4];
        float av[8] = {a0.x, a0.y, a0.z, a0.w, a1.x, a1.y, a1.z, a1.w};
        float bv[8] = {b0.x, b0.y, b0.z, b0.w, b1.x, b1.y, b1.z, b1.w};
#pragma unroll
        for (int i = 0; i < 8; ++i)
#pragma unroll
          for (int j = 0; j < 8; ++j) acc[i][j] = fmaf(av[i], bv[j], acc[i][j]);
      }
    }
    // epilogue: fused BCE for this o-tile
    const int og = o0 + obase;
    if (og < 784) {
      float4 d0 = *(const float4*)&decb[og];
      float4 d1 = *(const float4*)&decb[og + 4];
      float dbv[8] = {d0.x, d0.y, d0.z, d0.w, d1.x, d1.y, d1.z, d1.w};
#pragma unroll
      for (int i = 0; i < 8; ++i) {
        const int n = n0 + nbase + i;
        float4 y0 = *(const float4*)&y[n * 784 + og];
        float4 y1 = *(const float4*)&y[n * 784 + og + 4];
        float yv[8] = {y0.x, y0.y, y0.z, y0.w, y1.x, y1.y, y1.z, y1.w};
        float s = 0.f;
#pragma unroll
        for (int j = 0; j < 8; ++j) {
          float x = acc[i][j] + dbv[j];
          // softplus(x) = max(x,0) + log(1+exp(-|x|)); bce = y*min(sp-x,100)+(1-y)*min(sp,100)
          float spx = fmaxf(x, 0.f) + __logf(1.f + __expf(-fabsf(x)));
          float t2 = fminf(spx, 100.f);
          float t1 = fminf(spx - x, 100.f);
          s += t2 + yv[j] * (t1 - t2);
        }
        pr[i] += s;
      }
    }
  }
  // reduce over the 8 'tto' lanes holding the same n rows
#pragma unroll
  for (int i = 0; i < 8; ++i) {
    float v = pr[i];
    v += __shfl_xor(v, 1, 64);
    v += __shfl_xor(v, 2, 64);
    v += __shfl_xor(v, 4, 64);
    if (tto == 0) red[(nbase + i) * 2 + wo] = v;
  }
  __syncthreads();
  if (tid < 128) {
    float s = red[tid * 2] + red[tid * 2 + 1];
    lb[(n0 + tid) * 16 + k] = -(s / 100.0f);
  }
}

// ---------------- K5: HMM forward/backward (scaled linear domain) ----------------
// one block per sequence b. gamma/xi are normalized => all per-step scales cancel exactly.
__global__ __launch_bounds__(256, 2)
void k_hmm(const float* __restrict__ lb, const float* __restrict__ lpi,
           const float* __restrict__ lA, float* __restrict__ out) {
  __shared__ float btl[128 * 16];   // loaded as lb, overwritten in place with exp(lb - rowmax)
  __shared__ float ah[128 * 16];
  __shared__ float bh[128 * 16];
  __shared__ float braw[128 * 16];
  __shared__ float A_l[16 * 17];
  __shared__ float pi_l[16];
  __shared__ float sinv[128];
  const int tid = threadIdx.x;
  const int b = blockIdx.x;

  for (int idx = tid; idx < 512; idx += 256)
    *(float4*)&btl[idx * 4] = *(const float4*)&lb[b * 2048 + idx * 4];
  if (tid < 16) {  // A' row = softmax(log_A row) + 1e-9
    const int j = tid;
    float m = -1e30f;
#pragma unroll
    for (int q = 0; q < 16; ++q) m = fmaxf(m, lA[j * 16 + q]);
    float e[16]; float s = 0.f;
#pragma unroll
    for (int q = 0; q < 16; ++q) { e[q] = expf(lA[j * 16 + q] - m); s += e[q]; }
    float inv = 1.f / s;
#pragma unroll
    for (int q = 0; q < 16; ++q) A_l[j * 17 + q] = e[q] * inv + 1e-9f;
  } else if (tid == 16) {
    float m = -1e30f;
#pragma unroll
    for (int q = 0; q < 16; ++q) m = fmaxf(m, lpi[q]);
    float e[16]; float s = 0.f;
#pragma unroll
    for (int q = 0; q < 16; ++q) { e[q] = expf(lpi[q] - m); s += e[q]; }
    float inv = 1.f / s;
#pragma unroll
    for (int q = 0; q < 16; ++q) pi_l[q] = e[q] * inv + 1e-9f;
  }
  __syncthreads();
  if (tid < 128) {  // btilde = exp(lb - rowmax), in place
    const int t = tid;
    float v[16]; float m = -1e30f;
#pragma unroll
    for (int q = 0; q < 16; ++q) { v[q] = btl[t * 16 + q]; m = fmaxf(m, v[q]); }
#pragma unroll
    for (int q = 0; q < 16; ++q) btl[t * 16 + q] = expf(v[q] - m);
  }
  __syncthreads();
  const int lane = tid & 63;
  const int kk = lane & 15, grp = lane >> 4;
  if (tid < 64) {  // alpha_0
    float v = pi_l[kk] * btl[kk];
    float ss = v;
    ss += __shfl_xor(ss, 1, 64); ss += __shfl_xor(ss, 2, 64);
    ss += __shfl_xor(ss, 4, 64); ss += __shfl_xor(ss, 8, 64);
    if (grp == 0) ah[kk] = v / ss;
  } else if (tid < 128) {  // beta_{T-1} = 1
    if (grp == 0) bh[127 * 16 + kk] = 1.f;
  }
  __syncthreads();
  for (int s = 1; s < 128; ++s) {
    if (tid < 64) {  // forward step t = s
      const int t = s;
      float acc = 0.f;
#pragma unroll
      for (int jj = 0; jj < 4; ++jj) {
        int j = grp * 4 + jj;
        acc = fmaf(ah[(t - 1) * 16 + j], A_l[j * 17 + kk], acc);
      }
      acc += __shfl_xor(acc, 16, 64);
      acc += __shfl_xor(acc, 32, 64);
      float v = acc * btl[t * 16 + kk];
      float ss = v;
      ss += __shfl_xor(ss, 1, 64); ss += __shfl_xor(ss, 2, 64);
      ss += __shfl_xor(ss, 4, 64); ss += __shfl_xor(ss, 8, 64);
      if (grp == 0) ah[t * 16 + kk] = v / ss;
    } else if (tid < 128) {  // backward step t = 127 - s (kk plays the role of j)
      const int t = 127 - s;
      float acc = 0.f;
#pragma unroll
      for (int q = 0; q < 4; ++q) {
        int k2 = grp * 4 + q;
        acc = fmaf(A_l[kk * 17 + k2], btl[(t + 1) * 16 + k2] * bh[(t + 1) * 16 + k2], acc);
      }
      acc += __shfl_xor(acc, 16, 64);
      acc += __shfl_xor(acc, 32, 64);
      float ss = acc;
      ss += __shfl_xor(ss, 1, 64); ss += __shfl_xor(ss, 2, 64);
      ss += __shfl_xor(ss, 4, 64); ss += __shfl_xor(ss, 8, 64);
      if (grp == 0) { braw[t * 16 + kk] = acc; bh[t * 16 + kk] = acc / ss; }
    }
    __syncthreads();
  }
  if (tid < 128) {  // gamma
    const int t = tid;
    float g[16]; float s2 = 0.f;
#pragma unroll
    for (int q = 0; q < 16; ++q) { g[q] = ah[t * 16 + q] * bh[t * 16 + q]; s2 += g[q]; }
    float inv = 1.f / s2;
#pragma unroll
    for (int c = 0; c < 4; ++c) {
      float4 o;
      o.x = g[c * 4 + 0] * inv; o.y = g[c * 4 + 1] * inv;
      o.z = g[c * 4 + 2] * inv; o.w = g[c * 4 + 3] * inv;
      *(float4*)&out[(b * 128 + t) * 16 + c * 4] = o;
    }
  } else {  // xi normalizers: S[t] = sum_j ah[t,j]*braw[t,j]
    const int t = tid - 128;
    if (t < 127) {
      float s2 = 0.f;
#pragma unroll
      for (int q = 0; q < 16; ++q) s2 += ah[t * 16 + q] * braw[t * 16 + q];
      sinv[t] = 1.f / s2;
    }
  }
  __syncthreads();
  {  // xi[b,t,j,k]
    const int j = tid >> 4, k2 = tid & 15;
    const float Ajk = A_l[j * 17 + k2];
    float* xo = out + 65536 + b * 127 * 256;
    for (int t = 0; t < 127; ++t) {
      float val = ah[t * 16 + j] * Ajk * btl[(t + 1) * 16 + k2] * bh[(t + 1) * 16 + k2] * sinv[t];
      xo[t * 256 + tid] = val;
    }
  }
}

extern "C" void kernel_launch(void* const* d_in, const int* in_sizes, int n_in,
                              void* d_out, int out_size, void* d_ws, size_t ws_size,
                              hipStream_t stream) {
  (void)in_sizes; (void)n_in; (void)out_size; (void)ws_size;
  const float* y   = (const float*)d_in[0];   // (32,128,1,28,28) -> [4096][784]
  const float* ew1 = (const float*)d_in[1];   // (400,784)
  const float* eb1 = (const float*)d_in[2];   // (400,)
  const float* ew2 = (const float*)d_in[3];   // (32,400)
  const float* eb2 = (const float*)d_in[4];   // (32,)
  const float* dfw = (const float*)d_in[5];   // (400,32) : [:, :16]=Wz, [:,16:]=Wx
  const float* dfb = (const float*)d_in[6];   // (400,)
  const float* dw  = (const float*)d_in[7];   // (784,400)
  const float* db  = (const float*)d_in[8];   // (784,)
  const float* lpi = (const float*)d_in[9];   // (16,)
  const float* lA  = (const float*)d_in[10];  // (16,16)
  const float* eps = (const float*)d_in[11];  // (4096,16)
  float* out = (float*)d_out;                 // gamma (32,128,16) ++ xi (32,127,16,16)

  float* ws   = (float*)d_ws;
  float* h    = ws;              // 4096*400 = 1,638,400
  float* z    = h + 1638400;     // 4096*16  =    65,536
  float* base = z + 65536;       // 4096*400 = 1,638,400
  float* lb   = base + 1638400;  // 4096*16  =    65,536   (~13.6 MB total)

  k_enc1<<<dim3(64, 7), 256, 0, stream>>>(y, ew1, eb1, h);
  k_enc2z<<<1024, 128, 0, stream>>>(h, ew2, eb2, eps, z);
  k_base<<<256, 256, 0, stream>>>(z, dfw, dfb, base);
  k_dec<<<dim3(32, 16), 256, 0, stream>>>(base, dfw, dw, db, y, lb);
  k_hmm<<<32, 256, 0, stream>>>(lb, lpi, lA, out);
}

// Round 2
// 531.507 us; speedup vs baseline: 1.6442x; 1.6442x over previous
//
#include <hip/hip_runtime.h>
#include <math.h>

// Problem constants (B=32, T=128, K=16, L=16); N = 4096 tokens, 784 pixels, hidden 400.
// Pipeline:
//   k_prep : decw -> bf16 hi/lo, padded [896][448]
//   k_enc1 : h[4096,400]    = relu(y @ W1^T + b1)                (fp32 VALU)
//   k_enc2z: z[4096,16]                                          (fp32 VALU)
//   k_base : base_p[4096,448] = z @ Wz^T + dec_fc_b (zero-padded h>=400)
//   k_dec  : split-bf16 MFMA GEMM (Ah*Bh + Ah*Bl + Al*Bh) + fused BCE -> lb[4096,16]
//   k_hmm  : scaled linear-domain forward/backward -> gamma, xi

typedef short bf8v __attribute__((ext_vector_type(8)));    // 8 bf16 = 4 VGPRs (MFMA A/B frag)
typedef float f16v __attribute__((ext_vector_type(16)));   // MFMA C/D frag

static __device__ __forceinline__ unsigned short f2bf(float x) {
  unsigned u = __builtin_bit_cast(unsigned, x);
  u = (u + 0x7fffu + ((u >> 16) & 1u)) >> 16;   // RNE (no NaN/Inf in this pipeline)
  return (unsigned short)u;
}
static __device__ __forceinline__ float bf2f(unsigned short h) {
  unsigned u = ((unsigned)h) << 16;
  return __builtin_bit_cast(float, u);
}

// ---------------- k_prep: decw [784,400] -> dwhi/dwlo bf16 padded [896,448] ----------------
__global__ __launch_bounds__(256)
void k_prep(const float* __restrict__ dw, unsigned short* __restrict__ dwhi,
            unsigned short* __restrict__ dwlo) {
  int idx = blockIdx.x * 256 + threadIdx.x;  // over 896*448
  if (idx >= 896 * 448) return;
  int o = idx / 448, h2 = idx - o * 448;
  float v = (o < 784 && h2 < 400) ? dw[o * 400 + h2] : 0.f;
  unsigned short hi = f2bf(v);
  float lof = v - bf2f(hi);
  dwhi[idx] = hi;
  dwlo[idx] = f2bf(lof);
}

// ---------------- K1: h = relu(y @ W1^T + b1) ----------------
__global__ __launch_bounds__(256, 4)
void k_enc1(const float* __restrict__ y, const float* __restrict__ w1,
            const float* __restrict__ b1, float* __restrict__ hout) {
  __shared__ __align__(16) float a_lds[16 * 68];
  __shared__ __align__(16) float b_lds[16 * 68];
  const int tid = threadIdx.x;
  const int n0 = blockIdx.x * 64;
  const int i0 = blockIdx.y * 64;
  const int tm = tid & 15, ti = tid >> 4;
  const int lm = tid >> 2;
  const int lk = (tid & 3) << 2;
  const int irow = i0 + lm;
  float acc[4][4];
#pragma unroll
  for (int r = 0; r < 4; ++r)
#pragma unroll
    for (int c = 0; c < 4; ++c) acc[r][c] = 0.f;

  for (int k0 = 0; k0 < 784; k0 += 16) {
    __syncthreads();
    float4 av = *(const float4*)&y[(n0 + lm) * 784 + k0 + lk];
    float4 bv = make_float4(0.f, 0.f, 0.f, 0.f);
    if (irow < 400) bv = *(const float4*)&w1[irow * 784 + k0 + lk];
    a_lds[(lk + 0) * 68 + lm] = av.x;
    a_lds[(lk + 1) * 68 + lm] = av.y;
    a_lds[(lk + 2) * 68 + lm] = av.z;
    a_lds[(lk + 3) * 68 + lm] = av.w;
    b_lds[(lk + 0) * 68 + lm] = bv.x;
    b_lds[(lk + 1) * 68 + lm] = bv.y;
    b_lds[(lk + 2) * 68 + lm] = bv.z;
    b_lds[(lk + 3) * 68 + lm] = bv.w;
    __syncthreads();
#pragma unroll
    for (int kk = 0; kk < 16; ++kk) {
      float4 a = *(const float4*)&a_lds[kk * 68 + tm * 4];
      float4 b = *(const float4*)&b_lds[kk * 68 + ti * 4];
      float aa[4] = {a.x, a.y, a.z, a.w};
      float bb[4] = {b.x, b.y, b.z, b.w};
#pragma unroll
      for (int r = 0; r < 4; ++r)
#pragma unroll
        for (int c = 0; c < 4; ++c) acc[r][c] = fmaf(aa[r], bb[c], acc[r][c]);
    }
  }
  const int ic = i0 + ti * 4;
  if (ic < 400) {
    float4 bias = *(const float4*)&b1[ic];
    float bb[4] = {bias.x, bias.y, bias.z, bias.w};
#pragma unroll
    for (int r = 0; r < 4; ++r) {
      float4 o;
      o.x = fmaxf(acc[r][0] + bb[0], 0.f);
      o.y = fmaxf(acc[r][1] + bb[1], 0.f);
      o.z = fmaxf(acc[r][2] + bb[2], 0.f);
      o.w = fmaxf(acc[r][3] + bb[3], 0.f);
      *(float4*)&hout[(n0 + tm * 4 + r) * 400 + ic] = o;
    }
  }
}

// ---------------- K2: ml = h @ W2^T + b2, z = mu + eps*exp(0.5*logvar) ----------------
__global__ __launch_bounds__(128, 4)
void k_enc2z(const float* __restrict__ h, const float* __restrict__ w2,
             const float* __restrict__ b2, const float* __restrict__ eps,
             float* __restrict__ z) {
  __shared__ __align__(16) float h_lds[4 * 400];
  __shared__ __align__(16) float w2_lds[32 * 404];
  __shared__ float ml_lds[4 * 32];
  const int tid = threadIdx.x;
  const int n0 = blockIdx.x * 4;
  for (int idx = tid; idx < 400; idx += 128) {
    int r = idx / 100, c = idx % 100;
    *(float4*)&h_lds[r * 400 + c * 4] = *(const float4*)&h[(n0 + r) * 400 + c * 4];
  }
  for (int idx = tid; idx < 3200; idx += 128) {
    int r = idx / 100, c = idx % 100;
    *(float4*)&w2_lds[r * 404 + c * 4] = *(const float4*)&w2[r * 400 + c * 4];
  }
  __syncthreads();
  const int c_ = tid & 31, n_ = tid >> 5;
  float acc = 0.f;
  for (int q = 0; q < 100; ++q) {
    float4 hv = *(const float4*)&h_lds[n_ * 400 + q * 4];
    float4 wv = *(const float4*)&w2_lds[c_ * 404 + q * 4];
    acc += hv.x * wv.x + hv.y * wv.y + hv.z * wv.z + hv.w * wv.w;
  }
  ml_lds[n_ * 32 + c_] = acc + b2[c_];
  __syncthreads();
  if (tid < 64) {
    int n2 = tid >> 4, l = tid & 15;
    float mu = ml_lds[n2 * 32 + l];
    float lv = ml_lds[n2 * 32 + 16 + l];
    z[(n0 + n2) * 16 + l] = mu + eps[(n0 + n2) * 16 + l] * expf(0.5f * lv);
  }
}

// ---------------- K3: base_p = z @ Wz^T + dec_fc_b, padded [4096][448] ----------------
__global__ __launch_bounds__(256, 4)
void k_base(const float* __restrict__ z, const float* __restrict__ dfw,
            const float* __restrict__ dfb, float* __restrict__ basep) {
  __shared__ float z_lds[16 * 16];
  __shared__ __align__(16) float wz_lds[400 * 20];
  const int tid = threadIdx.x;
  const int n0 = blockIdx.x * 16;
  if (tid < 64) {
    int n = tid >> 2, c = (tid & 3) * 4;
    *(float4*)&z_lds[n * 16 + c] = *(const float4*)&z[(n0 + n) * 16 + c];
  }
  for (int idx = tid; idx < 1600; idx += 256) {
    int i = idx >> 2, c = (idx & 3) * 4;
    *(float4*)&wz_lds[i * 20 + c] = *(const float4*)&dfw[i * 32 + c];
  }
  __syncthreads();
  for (int idx = tid; idx < 7168; idx += 256) {  // 16 n * 448 padded cols
    int n = idx / 448, i = idx - n * 448;
    float acc = 0.f;
    if (i < 400) {
      acc = dfb[i];
#pragma unroll
      for (int q = 0; q < 4; ++q) {
        float4 zv = *(const float4*)&z_lds[n * 16 + q * 4];
        float4 wv = *(const float4*)&wz_lds[i * 20 + q * 4];
        acc += zv.x * wv.x + zv.y * wv.y + zv.z * wv.z + zv.w * wv.w;
      }
    }
    basep[(n0 + n) * 448 + i] = acc;
  }
}

// ---------------- K4: decoder GEMM via split-bf16 MFMA + fused BCE ----------------
// grid (16 k, 32 n-tiles); block 256 = 4 waves, each wave a 64x64 subtile of the
// 128n x 128o block tile. o-tiles: 7 x 128 (last 16 valid); h-chunks: 7 x 64 (400 + pad).
// LDS rows stride 72 bf16 = 144 B: 16B-aligned for ds_read_b128, bank-balanced.
#define AST 72
__global__ __launch_bounds__(256, 2)
void k_dec(const float* __restrict__ basep, const float* __restrict__ dfw,
           const unsigned short* __restrict__ dwhi, const unsigned short* __restrict__ dwlo,
           const float* __restrict__ decb, const float* __restrict__ y,
           float* __restrict__ lb) {
  __shared__ __align__(16) unsigned short Ahi[128 * AST];
  __shared__ __align__(16) unsigned short Alo[128 * AST];
  __shared__ __align__(16) unsigned short Bhi[128 * AST];
  __shared__ __align__(16) unsigned short Blo[128 * AST];
  __shared__ float wx[448];
  __shared__ float red[256];

  const int tid = threadIdx.x;
  const int k = blockIdx.x;
  const int n0 = blockIdx.y * 128;
  const int wav = tid >> 6, lane = tid & 63;
  const int wn = wav >> 1, wo = wav & 1;
  const int ln = lane & 31, kg = lane >> 5;

  for (int i = tid; i < 448; i += 256) wx[i] = (i < 400) ? dfw[i * 32 + 16 + k] : 0.f;

  float pr[2][16];
#pragma unroll
  for (int i = 0; i < 2; ++i)
#pragma unroll
    for (int r = 0; r < 16; ++r) pr[i][r] = 0.f;

  const int aoff0 = (wn * 64 + ln) * AST + kg * 8;
  const int aoff1 = aoff0 + 32 * AST;
  const int boff0 = (wo * 64 + ln) * AST + kg * 8;
  const int boff1 = boff0 + 32 * AST;

#pragma unroll 1
  for (int ot = 0; ot < 7; ++ot) {
    const int o0 = ot * 128;
    const bool full = (ot < 6);
    f16v acc[2][2];
#pragma unroll
    for (int i = 0; i < 2; ++i)
#pragma unroll
      for (int j = 0; j < 2; ++j)
#pragma unroll
        for (int r = 0; r < 16; ++r) acc[i][j][r] = 0.f;

#pragma unroll 1
    for (int hc = 0; hc < 7; ++hc) {
      const int h0 = hc * 64;
      __syncthreads();
      // stage B: 128 o-rows x 8 chunks of 8 bf16 (hi+lo)
#pragma unroll
      for (int it = 0; it < 4; ++it) {
        int idx = tid + it * 256;
        int r = idx >> 3, g = idx & 7;
        bf8v vh = *(const bf8v*)&dwhi[(o0 + r) * 448 + h0 + g * 8];
        bf8v vl = *(const bf8v*)&dwlo[(o0 + r) * 448 + h0 + g * 8];
        *(bf8v*)&Bhi[r * AST + g * 8] = vh;
        *(bf8v*)&Blo[r * AST + g * 8] = vl;
      }
      // stage A: hk = relu(base + wx_k), split hi/lo. 128 n-rows x 16 f4-chunks
#pragma unroll
      for (int it = 0; it < 8; ++it) {
        int idx = tid + it * 256;
        int r = idx >> 4, c4 = (idx & 15) * 4;
        float4 b = *(const float4*)&basep[(n0 + r) * 448 + h0 + c4];
        float xv[4] = {fmaxf(b.x + wx[h0 + c4 + 0], 0.f), fmaxf(b.y + wx[h0 + c4 + 1], 0.f),
                       fmaxf(b.z + wx[h0 + c4 + 2], 0.f), fmaxf(b.w + wx[h0 + c4 + 3], 0.f)};
        union { unsigned short u[4]; unsigned long long q; } uh, ul;
#pragma unroll
        for (int e = 0; e < 4; ++e) {
          unsigned short hb = f2bf(xv[e]);
          uh.u[e] = hb;
          ul.u[e] = f2bf(xv[e] - bf2f(hb));
        }
        *(unsigned long long*)&Ahi[r * AST + c4] = uh.q;
        *(unsigned long long*)&Alo[r * AST + c4] = ul.q;
      }
      __syncthreads();
#pragma unroll
      for (int kk = 0; kk < 4; ++kk) {
        const int ko = kk * 16;
        bf8v ah0 = *(const bf8v*)&Ahi[aoff0 + ko];
        bf8v ah1 = *(const bf8v*)&Ahi[aoff1 + ko];
        bf8v al0 = *(const bf8v*)&Alo[aoff0 + ko];
        bf8v al1 = *(const bf8v*)&Alo[aoff1 + ko];
        bf8v bh0 = *(const bf8v*)&Bhi[boff0 + ko];
        bf8v bh1 = *(const bf8v*)&Bhi[boff1 + ko];
        bf8v bl0 = *(const bf8v*)&Blo[boff0 + ko];
        bf8v bl1 = *(const bf8v*)&Blo[boff1 + ko];
        if (full || wo == 0) {
          acc[0][0] = __builtin_amdgcn_mfma_f32_32x32x16_bf16(ah0, bh0, acc[0][0], 0, 0, 0);
          acc[0][0] = __builtin_amdgcn_mfma_f32_32x32x16_bf16(ah0, bl0, acc[0][0], 0, 0, 0);
          acc[0][0] = __builtin_amdgcn_mfma_f32_32x32x16_bf16(al0, bh0, acc[0][0], 0, 0, 0);
          acc[1][0] = __builtin_amdgcn_mfma_f32_32x32x16_bf16(ah1, bh0, acc[1][0], 0, 0, 0);
          acc[1][0] = __builtin_amdgcn_mfma_f32_32x32x16_bf16(ah1, bl0, acc[1][0], 0, 0, 0);
          acc[1][0] = __builtin_amdgcn_mfma_f32_32x32x16_bf16(al1, bh0, acc[1][0], 0, 0, 0);
        }
        if (full) {
          acc[0][1] = __builtin_amdgcn_mfma_f32_32x32x16_bf16(ah0, bh1, acc[0][1], 0, 0, 0);
          acc[0][1] = __builtin_amdgcn_mfma_f32_32x32x16_bf16(ah0, bl1, acc[0][1], 0, 0, 0);
          acc[0][1] = __builtin_amdgcn_mfma_f32_32x32x16_bf16(al0, bh1, acc[0][1], 0, 0, 0);
          acc[1][1] = __builtin_amdgcn_mfma_f32_32x32x16_bf16(ah1, bh1, acc[1][1], 0, 0, 0);
          acc[1][1] = __builtin_amdgcn_mfma_f32_32x32x16_bf16(ah1, bl1, acc[1][1], 0, 0, 0);
          acc[1][1] = __builtin_amdgcn_mfma_f32_32x32x16_bf16(al1, bh1, acc[1][1], 0, 0, 0);
        }
      }
    }
    // epilogue: fused BCE.  C/D layout: col(o) = lane&31, row = (reg&3)+8*(reg>>2)+4*kg
#pragma unroll
    for (int j = 0; j < 2; ++j) {
      const int o = o0 + wo * 64 + j * 32 + ln;
      const bool valid = (o < 784);
      const float bias = valid ? decb[o] : 0.f;
#pragma unroll
      for (int i = 0; i < 2; ++i) {
        if (valid) {
#pragma unroll
          for (int reg = 0; reg < 16; ++reg) {
            const int row = wn * 64 + i * 32 + (reg & 3) + 8 * (reg >> 2) + 4 * kg;
            float x = acc[i][j][reg] + bias;
            float yv = y[(n0 + row) * 784 + o];
            float spx = fmaxf(x, 0.f) + __logf(1.f + __expf(-fabsf(x)));
            float t2 = fminf(spx, 100.f);
            float t1 = fminf(spx - x, 100.f);
            pr[i][reg] += t2 + yv * (t1 - t2);
          }
        }
      }
    }
  }
  // reduce bce partials across the 32 o-columns of each half-wave
#pragma unroll
  for (int i = 0; i < 2; ++i)
#pragma unroll
    for (int reg = 0; reg < 16; ++reg) {
      float v = pr[i][reg];
      v += __shfl_xor(v, 1, 64);
      v += __shfl_xor(v, 2, 64);
      v += __shfl_xor(v, 4, 64);
      v += __shfl_xor(v, 8, 64);
      v += __shfl_xor(v, 16, 64);
      if (ln == 0) {
        const int row = wn * 64 + i * 32 + (reg & 3) + 8 * (reg >> 2) + 4 * kg;
        red[wo * 128 + row] = v;
      }
    }
  __syncthreads();
  if (tid < 128) {
    float s = red[tid] + red[128 + tid];
    lb[(n0 + tid) * 16 + k] = -(s / 100.0f);
  }
}

// ---------------- K5: HMM forward/backward (scaled linear domain) ----------------
__global__ __launch_bounds__(256, 2)
void k_hmm(const float* __restrict__ lb, const float* __restrict__ lpi,
           const float* __restrict__ lA, float* __restrict__ out) {
  __shared__ float btl[128 * 16];
  __shared__ float ah[128 * 16];
  __shared__ float bh[128 * 16];
  __shared__ float braw[128 * 16];
  __shared__ float A_l[16 * 17];
  __shared__ float pi_l[16];
  __shared__ float sinv[128];
  const int tid = threadIdx.x;
  const int b = blockIdx.x;

  for (int idx = tid; idx < 512; idx += 256)
    *(float4*)&btl[idx * 4] = *(const float4*)&lb[b * 2048 + idx * 4];
  if (tid < 16) {
    const int j = tid;
    float m = -1e30f;
#pragma unroll
    for (int q = 0; q < 16; ++q) m = fmaxf(m, lA[j * 16 + q]);
    float e[16]; float s = 0.f;
#pragma unroll
    for (int q = 0; q < 16; ++q) { e[q] = expf(lA[j * 16 + q] - m); s += e[q]; }
    float inv = 1.f / s;
#pragma unroll
    for (int q = 0; q < 16; ++q) A_l[j * 17 + q] = e[q] * inv + 1e-9f;
  } else if (tid == 16) {
    float m = -1e30f;
#pragma unroll
    for (int q = 0; q < 16; ++q) m = fmaxf(m, lpi[q]);
    float e[16]; float s = 0.f;
#pragma unroll
    for (int q = 0; q < 16; ++q) { e[q] = expf(lpi[q] - m); s += e[q]; }
    float inv = 1.f / s;
#pragma unroll
    for (int q = 0; q < 16; ++q) pi_l[q] = e[q] * inv + 1e-9f;
  }
  __syncthreads();
  if (tid < 128) {
    const int t = tid;
    float v[16]; float m = -1e30f;
#pragma unroll
    for (int q = 0; q < 16; ++q) { v[q] = btl[t * 16 + q]; m = fmaxf(m, v[q]); }
#pragma unroll
    for (int q = 0; q < 16; ++q) btl[t * 16 + q] = expf(v[q] - m);
  }
  __syncthreads();
  const int lane = tid & 63;
  const int kk = lane & 15, grp = lane >> 4;
  if (tid < 64) {
    float v = pi_l[kk] * btl[kk];
    float ss = v;
    ss += __shfl_xor(ss, 1, 64); ss += __shfl_xor(ss, 2, 64);
    ss += __shfl_xor(ss, 4, 64); ss += __shfl_xor(ss, 8, 64);
    if (grp == 0) ah[kk] = v / ss;
  } else if (tid < 128) {
    if (grp == 0) bh[127 * 16 + kk] = 1.f;
  }
  __syncthreads();
  for (int s = 1; s < 128; ++s) {
    if (tid < 64) {
      const int t = s;
      float acc = 0.f;
#pragma unroll
      for (int jj = 0; jj < 4; ++jj) {
        int j = grp * 4 + jj;
        acc = fmaf(ah[(t - 1) * 16 + j], A_l[j * 17 + kk], acc);
      }
      acc += __shfl_xor(acc, 16, 64);
      acc += __shfl_xor(acc, 32, 64);
      float v = acc * btl[t * 16 + kk];
      float ss = v;
      ss += __shfl_xor(ss, 1, 64); ss += __shfl_xor(ss, 2, 64);
      ss += __shfl_xor(ss, 4, 64); ss += __shfl_xor(ss, 8, 64);
      if (grp == 0) ah[t * 16 + kk] = v / ss;
    } else if (tid < 128) {
      const int t = 127 - s;
      float acc = 0.f;
#pragma unroll
      for (int q = 0; q < 4; ++q) {
        int k2 = grp * 4 + q;
        acc = fmaf(A_l[kk * 17 + k2], btl[(t + 1) * 16 + k2] * bh[(t + 1) * 16 + k2], acc);
      }
      acc += __shfl_xor(acc, 16, 64);
      acc += __shfl_xor(acc, 32, 64);
      float ss = acc;
      ss += __shfl_xor(ss, 1, 64); ss += __shfl_xor(ss, 2, 64);
      ss += __shfl_xor(ss, 4, 64); ss += __shfl_xor(ss, 8, 64);
      if (grp == 0) { braw[t * 16 + kk] = acc; bh[t * 16 + kk] = acc / ss; }
    }
    __syncthreads();
  }
  if (tid < 128) {
    const int t = tid;
    float g[16]; float s2 = 0.f;
#pragma unroll
    for (int q = 0; q < 16; ++q) { g[q] = ah[t * 16 + q] * bh[t * 16 + q]; s2 += g[q]; }
    float inv = 1.f / s2;
#pragma unroll
    for (int c = 0; c < 4; ++c) {
      float4 o;
      o.x = g[c * 4 + 0] * inv; o.y = g[c * 4 + 1] * inv;
      o.z = g[c * 4 + 2] * inv; o.w = g[c * 4 + 3] * inv;
      *(float4*)&out[(b * 128 + t) * 16 + c * 4] = o;
    }
  } else {
    const int t = tid - 128;
    if (t < 127) {
      float s2 = 0.f;
#pragma unroll
      for (int q = 0; q < 16; ++q) s2 += ah[t * 16 + q] * braw[t * 16 + q];
      sinv[t] = 1.f / s2;
    }
  }
  __syncthreads();
  {
    const int j = tid >> 4, k2 = tid & 15;
    const float Ajk = A_l[j * 17 + k2];
    float* xo = out + 65536 + b * 127 * 256;
    for (int t = 0; t < 127; ++t) {
      float val = ah[t * 16 + j] * Ajk * btl[(t + 1) * 16 + k2] * bh[(t + 1) * 16 + k2] * sinv[t];
      xo[t * 256 + tid] = val;
    }
  }
}

extern "C" void kernel_launch(void* const* d_in, const int* in_sizes, int n_in,
                              void* d_out, int out_size, void* d_ws, size_t ws_size,
                              hipStream_t stream) {
  (void)in_sizes; (void)n_in; (void)out_size; (void)ws_size;
  const float* y   = (const float*)d_in[0];   // (4096,784)
  const float* ew1 = (const float*)d_in[1];   // (400,784)
  const float* eb1 = (const float*)d_in[2];   // (400,)
  const float* ew2 = (const float*)d_in[3];   // (32,400)
  const float* eb2 = (const float*)d_in[4];   // (32,)
  const float* dfw = (const float*)d_in[5];   // (400,32)
  const float* dfb = (const float*)d_in[6];   // (400,)
  const float* dw  = (const float*)d_in[7];   // (784,400)
  const float* db  = (const float*)d_in[8];   // (784,)
  const float* lpi = (const float*)d_in[9];   // (16,)
  const float* lA  = (const float*)d_in[10];  // (16,16)
  const float* eps = (const float*)d_in[11];  // (4096,16)
  float* out = (float*)d_out;

  float* ws = (float*)d_ws;
  // region0 (reused): h [4096*400] then base_p [4096*448]
  float* h     = ws;
  float* basep = ws;                          // overwrites h after enc2z consumed it
  float* z     = ws + 1835008;
  float* lb    = z + 65536;
  unsigned short* dwhi = (unsigned short*)(lb + 65536);        // [896*448] bf16
  unsigned short* dwlo = dwhi + 896 * 448;                     // total ws ~9.5 MB

  k_prep<<<(896 * 448 + 255) / 256, 256, 0, stream>>>(dw, dwhi, dwlo);
  k_enc1<<<dim3(64, 7), 256, 0, stream>>>(y, ew1, eb1, h);
  k_enc2z<<<1024, 128, 0, stream>>>(h, ew2, eb2, eps, z);
  k_base<<<256, 256, 0, stream>>>(z, dfw, dfb, basep);
  k_dec<<<dim3(16, 32), 256, 0, stream>>>(basep, dfw, dwhi, dwlo, db, y, lb);
  k_hmm<<<32, 256, 0, stream>>>(lb, lpi, lA, out);
}

// Round 3
// 394.418 us; speedup vs baseline: 2.2157x; 1.3476x over previous
//
#include <hip/hip_runtime.h>
#include <math.h>

// Problem constants (B=32, T=128, K=16, L=16); N = 4096 tokens, 784 pixels, hidden 400.
// Pipeline:
//   k_prep : decw -> bf16 hi/lo [896][448]; enc w1 -> bf16 hi/lo [512][800]
//   k_enc1 : h[4096,400] = relu(y @ W1^T + b1)        (split-bf16 MFMA, 3-term)
//   k_enc2z: z[4096,16]                               (fp32 VALU)
//   k_base : base_p[4096,448] = z @ Wz^T + dec_fc_b   (zero-padded h>=400)
//   k_dec  : split-bf16 MFMA GEMM + fused BCE -> lb[4096,16]
//   k_hmm  : scaled linear fwd/bwd -> gamma + state arrays (ah, pb, sinv, Al)
//   k_xi   : xi[32,127,16,16] fully parallel from state arrays

typedef short bf8v __attribute__((ext_vector_type(8)));    // 8 bf16 (MFMA A/B frag)
typedef float f16v __attribute__((ext_vector_type(16)));   // MFMA C/D frag

static __device__ __forceinline__ unsigned short f2bf(float x) {
  unsigned u = __builtin_bit_cast(unsigned, x);
  u = (u + 0x7fffu + ((u >> 16) & 1u)) >> 16;   // RNE
  return (unsigned short)u;
}
// trunc split: hi = mantissa-truncated bf16 (exact prefix), lo = residual (RNE bf16).
// Combined representation error ~2^-17 relative — same class as 3-term omission error.
static __device__ __forceinline__ void tsplit(float x, unsigned short& hi, unsigned short& lo) {
  unsigned u = __builtin_bit_cast(unsigned, x);
  hi = (unsigned short)(u >> 16);
  float hf = __builtin_bit_cast(float, u & 0xffff0000u);
  lo = f2bf(x - hf);
}

// ---------------- k_prep: split decw [784,400]->[896,448] and w1 [400,784]->[512,800] ----
__global__ __launch_bounds__(256)
void k_prep(const float* __restrict__ dw, const float* __restrict__ ew1,
            unsigned short* __restrict__ dwhi, unsigned short* __restrict__ dwlo,
            unsigned short* __restrict__ w1hi, unsigned short* __restrict__ w1lo) {
  int idx = blockIdx.x * 256 + threadIdx.x;
  if (idx < 896 * 448) {
    int o = idx / 448, h2 = idx - o * 448;
    float v = (o < 784 && h2 < 400) ? dw[o * 400 + h2] : 0.f;
    unsigned short hi, lo; tsplit(v, hi, lo);
    dwhi[idx] = hi; dwlo[idx] = lo;
  } else if (idx < 896 * 448 + 512 * 800) {
    int j = idx - 896 * 448;
    int i = j / 800, kc = j - i * 800;
    float v = (i < 400 && kc < 784) ? ew1[i * 784 + kc] : 0.f;
    unsigned short hi, lo; tsplit(v, hi, lo);
    w1hi[j] = hi; w1lo[j] = lo;
  }
}

#define AST 40   // LDS row stride (bf16 elems) for 32-wide h-chunks; 80 B, 16B-aligned

// ---------------- K1: h = relu(y @ W1^T + b1) via split-bf16 MFMA ----------------
// grid (4 i-tiles of 128, 64 n-tiles of 64); block 256 = 4 waves (2n x 2i), wave 32n x 64i.
__global__ __launch_bounds__(256, 2)
void k_enc1(const float* __restrict__ y, const unsigned short* __restrict__ w1hi,
            const unsigned short* __restrict__ w1lo, const float* __restrict__ b1,
            float* __restrict__ hout) {
  __shared__ __align__(16) unsigned short Ahi[64 * AST];
  __shared__ __align__(16) unsigned short Alo[64 * AST];
  __shared__ __align__(16) unsigned short Bhi[128 * AST];
  __shared__ __align__(16) unsigned short Blo[128 * AST];
  const int tid = threadIdx.x;
  const int i0 = blockIdx.x * 128;
  const int n0 = blockIdx.y * 64;
  const int wav = tid >> 6, lane = tid & 63;
  const int wn = wav >> 1, wi = wav & 1;
  const int ln = lane & 31, kg = lane >> 5;

  f16v acc[2];
#pragma unroll
  for (int j = 0; j < 2; ++j)
#pragma unroll
    for (int r = 0; r < 16; ++r) acc[j][r] = 0.f;

  const int ar = tid >> 3, ac4 = (tid & 7) * 4;   // A: 64 rows x 8 f4 = 512, 2/thread
  const int br = tid >> 2, bg = (tid & 3) * 8;    // B: 128 rows x 4 x8 = 512, 2/thread

#pragma unroll 1
  for (int hc = 0; hc < 25; ++hc) {
    const int h0 = hc * 32;
    __syncthreads();
    // stage A = y split (guard k<784)
#pragma unroll
    for (int it = 0; it < 2; ++it) {
      int r = ar + 32 * it;
      float4 a = make_float4(0.f, 0.f, 0.f, 0.f);
      if (h0 + ac4 < 784) a = *(const float4*)&y[(n0 + r) * 784 + h0 + ac4];
      float xv[4] = {a.x, a.y, a.z, a.w};
      union { unsigned short u[4]; unsigned long long q; } uh, ul;
#pragma unroll
      for (int e = 0; e < 4; ++e) tsplit(xv[e], uh.u[e], ul.u[e]);
      *(unsigned long long*)&Ahi[r * AST + ac4] = uh.q;
      *(unsigned long long*)&Alo[r * AST + ac4] = ul.q;
    }
    // stage B = pre-split w1 (padded, no guard)
#pragma unroll
    for (int it = 0; it < 2; ++it) {
      int r = br + 64 * it;
      *(bf8v*)&Bhi[r * AST + bg] = *(const bf8v*)&w1hi[(i0 + r) * 800 + h0 + bg];
      *(bf8v*)&Blo[r * AST + bg] = *(const bf8v*)&w1lo[(i0 + r) * 800 + h0 + bg];
    }
    __syncthreads();
#pragma unroll
    for (int kk = 0; kk < 2; ++kk) {
      const int ko = kk * 16 + kg * 8;
      bf8v ah = *(const bf8v*)&Ahi[(wn * 32 + ln) * AST + ko];
      bf8v al = *(const bf8v*)&Alo[(wn * 32 + ln) * AST + ko];
      bf8v bh0 = *(const bf8v*)&Bhi[(wi * 64 + ln) * AST + ko];
      bf8v bh1 = *(const bf8v*)&Bhi[(wi * 64 + 32 + ln) * AST + ko];
      bf8v bl0 = *(const bf8v*)&Blo[(wi * 64 + ln) * AST + ko];
      bf8v bl1 = *(const bf8v*)&Blo[(wi * 64 + 32 + ln) * AST + ko];
      acc[0] = __builtin_amdgcn_mfma_f32_32x32x16_bf16(ah, bh0, acc[0], 0, 0, 0);
      acc[0] = __builtin_amdgcn_mfma_f32_32x32x16_bf16(ah, bl0, acc[0], 0, 0, 0);
      acc[0] = __builtin_amdgcn_mfma_f32_32x32x16_bf16(al, bh0, acc[0], 0, 0, 0);
      acc[1] = __builtin_amdgcn_mfma_f32_32x32x16_bf16(ah, bh1, acc[1], 0, 0, 0);
      acc[1] = __builtin_amdgcn_mfma_f32_32x32x16_bf16(ah, bl1, acc[1], 0, 0, 0);
      acc[1] = __builtin_amdgcn_mfma_f32_32x32x16_bf16(al, bh1, acc[1], 0, 0, 0);
    }
  }
  // epilogue: C col(i) = ln, row(n) = (reg&3)+8*(reg>>2)+4*kg
#pragma unroll
  for (int j = 0; j < 2; ++j) {
    const int i = i0 + wi * 64 + j * 32 + ln;
    if (i < 400) {
      const float bias = b1[i];
#pragma unroll
      for (int reg = 0; reg < 16; ++reg) {
        const int row = n0 + wn * 32 + (reg & 3) + 8 * (reg >> 2) + 4 * kg;
        hout[row * 400 + i] = fmaxf(acc[j][reg] + bias, 0.f);
      }
    }
  }
}

// ---------------- K2: ml = h @ W2^T + b2, z = mu + eps*exp(0.5*logvar) ----------------
__global__ __launch_bounds__(128, 4)
void k_enc2z(const float* __restrict__ h, const float* __restrict__ w2,
             const float* __restrict__ b2, const float* __restrict__ eps,
             float* __restrict__ z) {
  __shared__ __align__(16) float h_lds[4 * 400];
  __shared__ __align__(16) float w2_lds[32 * 404];
  __shared__ float ml_lds[4 * 32];
  const int tid = threadIdx.x;
  const int n0 = blockIdx.x * 4;
  for (int idx = tid; idx < 400; idx += 128) {
    int r = idx / 100, c = idx % 100;
    *(float4*)&h_lds[r * 400 + c * 4] = *(const float4*)&h[(n0 + r) * 400 + c * 4];
  }
  for (int idx = tid; idx < 3200; idx += 128) {
    int r = idx / 100, c = idx % 100;
    *(float4*)&w2_lds[r * 404 + c * 4] = *(const float4*)&w2[r * 400 + c * 4];
  }
  __syncthreads();
  const int c_ = tid & 31, n_ = tid >> 5;
  float acc = 0.f;
  for (int q = 0; q < 100; ++q) {
    float4 hv = *(const float4*)&h_lds[n_ * 400 + q * 4];
    float4 wv = *(const float4*)&w2_lds[c_ * 404 + q * 4];
    acc += hv.x * wv.x + hv.y * wv.y + hv.z * wv.z + hv.w * wv.w;
  }
  ml_lds[n_ * 32 + c_] = acc + b2[c_];
  __syncthreads();
  if (tid < 64) {
    int n2 = tid >> 4, l = tid & 15;
    float mu = ml_lds[n2 * 32 + l];
    float lv = ml_lds[n2 * 32 + 16 + l];
    z[(n0 + n2) * 16 + l] = mu + eps[(n0 + n2) * 16 + l] * expf(0.5f * lv);
  }
}

// ---------------- K3: base_p = z @ Wz^T + dec_fc_b, padded [4096][448] ----------------
__global__ __launch_bounds__(256, 4)
void k_base(const float* __restrict__ z, const float* __restrict__ dfw,
            const float* __restrict__ dfb, float* __restrict__ basep) {
  __shared__ float z_lds[16 * 16];
  __shared__ __align__(16) float wz_lds[400 * 20];
  const int tid = threadIdx.x;
  const int n0 = blockIdx.x * 16;
  if (tid < 64) {
    int n = tid >> 2, c = (tid & 3) * 4;
    *(float4*)&z_lds[n * 16 + c] = *(const float4*)&z[(n0 + n) * 16 + c];
  }
  for (int idx = tid; idx < 1600; idx += 256) {
    int i = idx >> 2, c = (idx & 3) * 4;
    *(float4*)&wz_lds[i * 20 + c] = *(const float4*)&dfw[i * 32 + c];
  }
  __syncthreads();
  for (int idx = tid; idx < 7168; idx += 256) {
    int n = idx / 448, i = idx - n * 448;
    float acc = 0.f;
    if (i < 400) {
      acc = dfb[i];
#pragma unroll
      for (int q = 0; q < 4; ++q) {
        float4 zv = *(const float4*)&z_lds[n * 16 + q * 4];
        float4 wv = *(const float4*)&wz_lds[i * 20 + q * 4];
        acc += zv.x * wv.x + zv.y * wv.y + zv.z * wv.z + zv.w * wv.w;
      }
    }
    basep[(n0 + n) * 448 + i] = acc;
  }
}

// ---------------- K4: decoder GEMM via split-bf16 MFMA + fused BCE ----------------
// grid (16 k, 32 n-tiles of 128); block 256 = 4 waves (2n x 2o), wave 64x64.
// o-tiles: 7 x 128; h-chunks: 14 x 32. A globals register-prefetched across MFMA phase.
__global__ __launch_bounds__(256, 2)
void k_dec(const float* __restrict__ basep, const float* __restrict__ dfw,
           const unsigned short* __restrict__ dwhi, const unsigned short* __restrict__ dwlo,
           const float* __restrict__ decb, const float* __restrict__ y,
           float* __restrict__ lb) {
  __shared__ __align__(16) unsigned short Ahi[128 * AST];
  __shared__ __align__(16) unsigned short Alo[128 * AST];
  __shared__ __align__(16) unsigned short Bhi[128 * AST];
  __shared__ __align__(16) unsigned short Blo[128 * AST];
  __shared__ float wx[448];
  __shared__ float red[256];

  const int tid = threadIdx.x;
  const int k = blockIdx.x;
  const int n0 = blockIdx.y * 128;
  const int wav = tid >> 6, lane = tid & 63;
  const int wn = wav >> 1, wo = wav & 1;
  const int ln = lane & 31, kg = lane >> 5;

  for (int i = tid; i < 448; i += 256) wx[i] = (i < 400) ? dfw[i * 32 + 16 + k] : 0.f;

  float pr[2][16];
#pragma unroll
  for (int i = 0; i < 2; ++i)
#pragma unroll
    for (int r = 0; r < 16; ++r) pr[i][r] = 0.f;

  const int ar = tid >> 3, ac4 = (tid & 7) * 4;   // A: 128 rows x 8 f4, 4/thread
  const int br = tid >> 2, bg = (tid & 3) * 8;    // B: 128 rows x 4 x8, 2/thread
  const float* aptr = basep + (long)(n0 + ar) * 448 + ac4;

  // prefetch A chunk 0
  float4 apf[4];
#pragma unroll
  for (int it = 0; it < 4; ++it) apf[it] = *(const float4*)&aptr[(32 * it) * 448];

#pragma unroll 1
  for (int ot = 0; ot < 7; ++ot) {
    const int o0 = ot * 128;
    const bool full = (ot < 6);
    f16v acc[2][2];
#pragma unroll
    for (int i = 0; i < 2; ++i)
#pragma unroll
      for (int j = 0; j < 2; ++j)
#pragma unroll
        for (int r = 0; r < 16; ++r) acc[i][j][r] = 0.f;

#pragma unroll 1
    for (int hc = 0; hc < 14; ++hc) {
      const int h0 = hc * 32;
      // B loads for this chunk (short latency, L2-hot)
      bf8v bhv[2], blv[2];
#pragma unroll
      for (int it = 0; it < 2; ++it) {
        int r = br + 64 * it;
        bhv[it] = *(const bf8v*)&dwhi[(o0 + r) * 448 + h0 + bg];
        blv[it] = *(const bf8v*)&dwlo[(o0 + r) * 448 + h0 + bg];
      }
      __syncthreads();   // prev MFMA done reading LDS
      // convert prefetched A (relu + trunc-split) and store
      {
        float4 w = *(const float4*)&wx[h0 + ac4];
#pragma unroll
        for (int it = 0; it < 4; ++it) {
          int r = ar + 32 * it;
          float xv[4] = {fmaxf(apf[it].x + w.x, 0.f), fmaxf(apf[it].y + w.y, 0.f),
                         fmaxf(apf[it].z + w.z, 0.f), fmaxf(apf[it].w + w.w, 0.f)};
          union { unsigned short u[4]; unsigned long long q; } uh, ul;
#pragma unroll
          for (int e = 0; e < 4; ++e) tsplit(xv[e], uh.u[e], ul.u[e]);
          *(unsigned long long*)&Ahi[r * AST + ac4] = uh.q;
          *(unsigned long long*)&Alo[r * AST + ac4] = ul.q;
        }
      }
#pragma unroll
      for (int it = 0; it < 2; ++it) {
        int r = br + 64 * it;
        *(bf8v*)&Bhi[r * AST + bg] = bhv[it];
        *(bf8v*)&Blo[r * AST + bg] = blv[it];
      }
      __syncthreads();   // LDS ready
      // prefetch next A chunk (in flight during MFMA below)
      {
        const int hcn = (hc == 13) ? 0 : hc + 1;
        if (!(ot == 6 && hc == 13)) {
#pragma unroll
          for (int it = 0; it < 4; ++it)
            apf[it] = *(const float4*)&aptr[(32 * it) * 448 + hcn * 32];
        }
      }
#pragma unroll
      for (int kk = 0; kk < 2; ++kk) {
        const int ko = kk * 16 + kg * 8;
        bf8v ah0 = *(const bf8v*)&Ahi[(wn * 64 + ln) * AST + ko];
        bf8v ah1 = *(const bf8v*)&Ahi[(wn * 64 + 32 + ln) * AST + ko];
        bf8v al0 = *(const bf8v*)&Alo[(wn * 64 + ln) * AST + ko];
        bf8v al1 = *(const bf8v*)&Alo[(wn * 64 + 32 + ln) * AST + ko];
        bf8v bh0 = *(const bf8v*)&Bhi[(wo * 64 + ln) * AST + ko];
        bf8v bh1 = *(const bf8v*)&Bhi[(wo * 64 + 32 + ln) * AST + ko];
        bf8v bl0 = *(const bf8v*)&Blo[(wo * 64 + ln) * AST + ko];
        bf8v bl1 = *(const bf8v*)&Blo[(wo * 64 + 32 + ln) * AST + ko];
        if (full || wo == 0) {
          acc[0][0] = __builtin_amdgcn_mfma_f32_32x32x16_bf16(ah0, bh0, acc[0][0], 0, 0, 0);
          acc[0][0] = __builtin_amdgcn_mfma_f32_32x32x16_bf16(ah0, bl0, acc[0][0], 0, 0, 0);
          acc[0][0] = __builtin_amdgcn_mfma_f32_32x32x16_bf16(al0, bh0, acc[0][0], 0, 0, 0);
          acc[1][0] = __builtin_amdgcn_mfma_f32_32x32x16_bf16(ah1, bh0, acc[1][0], 0, 0, 0);
          acc[1][0] = __builtin_amdgcn_mfma_f32_32x32x16_bf16(ah1, bl0, acc[1][0], 0, 0, 0);
          acc[1][0] = __builtin_amdgcn_mfma_f32_32x32x16_bf16(al1, bh0, acc[1][0], 0, 0, 0);
        }
        if (full) {
          acc[0][1] = __builtin_amdgcn_mfma_f32_32x32x16_bf16(ah0, bh1, acc[0][1], 0, 0, 0);
          acc[0][1] = __builtin_amdgcn_mfma_f32_32x32x16_bf16(ah0, bl1, acc[0][1], 0, 0, 0);
          acc[0][1] = __builtin_amdgcn_mfma_f32_32x32x16_bf16(al0, bh1, acc[0][1], 0, 0, 0);
          acc[1][1] = __builtin_amdgcn_mfma_f32_32x32x16_bf16(ah1, bh1, acc[1][1], 0, 0, 0);
          acc[1][1] = __builtin_amdgcn_mfma_f32_32x32x16_bf16(ah1, bl1, acc[1][1], 0, 0, 0);
          acc[1][1] = __builtin_amdgcn_mfma_f32_32x32x16_bf16(al1, bh1, acc[1][1], 0, 0, 0);
        }
      }
    }
    // epilogue: fused BCE. C/D: col(o) = ln, row = (reg&3)+8*(reg>>2)+4*kg
#pragma unroll
    for (int j = 0; j < 2; ++j) {
      const int o = o0 + wo * 64 + j * 32 + ln;
      const bool valid = (o < 784);
      const float bias = valid ? decb[o] : 0.f;
#pragma unroll
      for (int i = 0; i < 2; ++i) {
        if (valid) {
#pragma unroll
          for (int reg = 0; reg < 16; ++reg) {
            const int row = wn * 64 + i * 32 + (reg & 3) + 8 * (reg >> 2) + 4 * kg;
            float x = acc[i][j][reg] + bias;
            float yv = y[(n0 + row) * 784 + o];
            float spx = fmaxf(x, 0.f) + __logf(1.f + __expf(-fabsf(x)));
            float t2 = fminf(spx, 100.f);
            float t1 = fminf(spx - x, 100.f);
            pr[i][reg] += t2 + yv * (t1 - t2);
          }
        }
      }
    }
  }
#pragma unroll
  for (int i = 0; i < 2; ++i)
#pragma unroll
    for (int reg = 0; reg < 16; ++reg) {
      float v = pr[i][reg];
      v += __shfl_xor(v, 1, 64);
      v += __shfl_xor(v, 2, 64);
      v += __shfl_xor(v, 4, 64);
      v += __shfl_xor(v, 8, 64);
      v += __shfl_xor(v, 16, 64);
      if (ln == 0) {
        const int row = wn * 64 + i * 32 + (reg & 3) + 8 * (reg >> 2) + 4 * kg;
        red[wo * 128 + row] = v;
      }
    }
  __syncthreads();
  if (tid < 128) {
    float s = red[tid] + red[128 + tid];
    lb[(n0 + tid) * 16 + k] = -(s / 100.0f);
  }
}

// ---------------- K5: HMM fwd/bwd (scaled linear) -> gamma + state for k_xi ----------------
__global__ __launch_bounds__(256, 2)
void k_hmm(const float* __restrict__ lb, const float* __restrict__ lpi,
           const float* __restrict__ lA, float* __restrict__ out,
           float* __restrict__ g_ah, float* __restrict__ g_pb,
           float* __restrict__ g_sinv, float* __restrict__ g_Al) {
  __shared__ float btl[128 * 16];
  __shared__ float ah[128 * 16];
  __shared__ float bh[128 * 16];
  __shared__ float braw[128 * 16];
  __shared__ float A_l[16 * 17];
  __shared__ float pi_l[16];
  const int tid = threadIdx.x;
  const int b = blockIdx.x;

  for (int idx = tid; idx < 512; idx += 256)
    *(float4*)&btl[idx * 4] = *(const float4*)&lb[b * 2048 + idx * 4];
  if (tid < 16) {
    const int j = tid;
    float m = -1e30f;
#pragma unroll
    for (int q = 0; q < 16; ++q) m = fmaxf(m, lA[j * 16 + q]);
    float e[16]; float s = 0.f;
#pragma unroll
    for (int q = 0; q < 16; ++q) { e[q] = expf(lA[j * 16 + q] - m); s += e[q]; }
    float inv = 1.f / s;
#pragma unroll
    for (int q = 0; q < 16; ++q) {
      float v = e[q] * inv + 1e-9f;
      A_l[j * 17 + q] = v;
      g_Al[j * 16 + q] = v;   // same value from every block — benign
    }
  } else if (tid == 16) {
    float m = -1e30f;
#pragma unroll
    for (int q = 0; q < 16; ++q) m = fmaxf(m, lpi[q]);
    float e[16]; float s = 0.f;
#pragma unroll
    for (int q = 0; q < 16; ++q) { e[q] = expf(lpi[q] - m); s += e[q]; }
    float inv = 1.f / s;
#pragma unroll
    for (int q = 0; q < 16; ++q) pi_l[q] = e[q] * inv + 1e-9f;
  }
  __syncthreads();
  if (tid < 128) {
    const int t = tid;
    float v[16]; float m = -1e30f;
#pragma unroll
    for (int q = 0; q < 16; ++q) { v[q] = btl[t * 16 + q]; m = fmaxf(m, v[q]); }
#pragma unroll
    for (int q = 0; q < 16; ++q) btl[t * 16 + q] = expf(v[q] - m);
  }
  __syncthreads();
  const int lane = tid & 63;
  const int kk = lane & 15, grp = lane >> 4;
  if (tid < 64) {
    float v = pi_l[kk] * btl[kk];
    float ss = v;
    ss += __shfl_xor(ss, 1, 64); ss += __shfl_xor(ss, 2, 64);
    ss += __shfl_xor(ss, 4, 64); ss += __shfl_xor(ss, 8, 64);
    if (grp == 0) ah[kk] = v / ss;
  } else if (tid < 128) {
    if (grp == 0) bh[127 * 16 + kk] = 1.f;
  }
  __syncthreads();
  for (int s = 1; s < 128; ++s) {
    if (tid < 64) {
      const int t = s;
      float acc = 0.f;
#pragma unroll
      for (int jj = 0; jj < 4; ++jj) {
        int j = grp * 4 + jj;
        acc = fmaf(ah[(t - 1) * 16 + j], A_l[j * 17 + kk], acc);
      }
      acc += __shfl_xor(acc, 16, 64);
      acc += __shfl_xor(acc, 32, 64);
      float v = acc * btl[t * 16 + kk];
      float ss = v;
      ss += __shfl_xor(ss, 1, 64); ss += __shfl_xor(ss, 2, 64);
      ss += __shfl_xor(ss, 4, 64); ss += __shfl_xor(ss, 8, 64);
      if (grp == 0) ah[t * 16 + kk] = v / ss;
    } else if (tid < 128) {
      const int t = 127 - s;
      float acc = 0.f;
#pragma unroll
      for (int q = 0; q < 4; ++q) {
        int k2 = grp * 4 + q;
        acc = fmaf(A_l[kk * 17 + k2], btl[(t + 1) * 16 + k2] * bh[(t + 1) * 16 + k2], acc);
      }
      acc += __shfl_xor(acc, 16, 64);
      acc += __shfl_xor(acc, 32, 64);
      float ss = acc;
      ss += __shfl_xor(ss, 1, 64); ss += __shfl_xor(ss, 2, 64);
      ss += __shfl_xor(ss, 4, 64); ss += __shfl_xor(ss, 8, 64);
      if (grp == 0) { braw[t * 16 + kk] = acc; bh[t * 16 + kk] = acc / ss; }
    }
    __syncthreads();
  }
  if (tid < 128) {
    const int t = tid;
    float g[16]; float s2 = 0.f;
#pragma unroll
    for (int q = 0; q < 16; ++q) { g[q] = ah[t * 16 + q] * bh[t * 16 + q]; s2 += g[q]; }
    float inv = 1.f / s2;
#pragma unroll
    for (int c = 0; c < 4; ++c) {
      float4 o;
      o.x = g[c * 4 + 0] * inv; o.y = g[c * 4 + 1] * inv;
      o.z = g[c * 4 + 2] * inv; o.w = g[c * 4 + 3] * inv;
      *(float4*)&out[(b * 128 + t) * 16 + c * 4] = o;
      float4 av = *(float4*)&ah[t * 16 + c * 4];
      *(float4*)&g_ah[(b * 128 + t) * 16 + c * 4] = av;
      float4 p;
      p.x = btl[t * 16 + c * 4 + 0] * bh[t * 16 + c * 4 + 0];
      p.y = btl[t * 16 + c * 4 + 1] * bh[t * 16 + c * 4 + 1];
      p.z = btl[t * 16 + c * 4 + 2] * bh[t * 16 + c * 4 + 2];
      p.w = btl[t * 16 + c * 4 + 3] * bh[t * 16 + c * 4 + 3];
      *(float4*)&g_pb[(b * 128 + t) * 16 + c * 4] = p;
    }
  } else {
    const int t = tid - 128;
    if (t < 127) {
      float s2 = 0.f;
#pragma unroll
      for (int q = 0; q < 16; ++q) s2 += ah[t * 16 + q] * braw[t * 16 + q];
      g_sinv[b * 128 + t] = 1.f / s2;
    }
  }
}

// ---------------- K6: xi[b,t,j,k] fully parallel ----------------
__global__ __launch_bounds__(256)
void k_xi(const float* __restrict__ g_ah, const float* __restrict__ g_pb,
          const float* __restrict__ g_sinv, const float* __restrict__ g_Al,
          float* __restrict__ out) {
  const int b = blockIdx.x, t = blockIdx.y;
  const int tid = threadIdx.x;
  const int j = tid >> 4, k2 = tid & 15;
  float val = g_ah[(b * 128 + t) * 16 + j] * g_Al[j * 16 + k2] *
              g_pb[(b * 128 + t + 1) * 16 + k2] * g_sinv[b * 128 + t];
  out[65536 + (b * 127 + t) * 256 + tid] = val;
}

extern "C" void kernel_launch(void* const* d_in, const int* in_sizes, int n_in,
                              void* d_out, int out_size, void* d_ws, size_t ws_size,
                              hipStream_t stream) {
  (void)in_sizes; (void)n_in; (void)out_size; (void)ws_size;
  const float* y   = (const float*)d_in[0];   // (4096,784)
  const float* ew1 = (const float*)d_in[1];   // (400,784)
  const float* eb1 = (const float*)d_in[2];   // (400,)
  const float* ew2 = (const float*)d_in[3];   // (32,400)
  const float* eb2 = (const float*)d_in[4];   // (32,)
  const float* dfw = (const float*)d_in[5];   // (400,32)
  const float* dfb = (const float*)d_in[6];   // (400,)
  const float* dw  = (const float*)d_in[7];   // (784,400)
  const float* db  = (const float*)d_in[8];   // (784,)
  const float* lpi = (const float*)d_in[9];   // (16,)
  const float* lA  = (const float*)d_in[10];  // (16,16)
  const float* eps = (const float*)d_in[11];  // (4096,16)
  float* out = (float*)d_out;

  float* ws = (float*)d_ws;
  // region0: h [4096*400] then base_p [4096*448] (h consumed by enc2z before k_base)
  float* h      = ws;
  float* basep  = ws;
  float* z      = ws + 1835008;
  float* lb     = z + 65536;
  unsigned short* dwhi = (unsigned short*)(lb + 65536);   // 896*448
  unsigned short* dwlo = dwhi + 896 * 448;
  unsigned short* w1hi = dwlo + 896 * 448;                // 512*800
  unsigned short* w1lo = w1hi + 512 * 800;
  float* g_ah   = (float*)(w1lo + 512 * 800);             // 65536
  float* g_pb   = g_ah + 65536;
  float* g_sinv = g_pb + 65536;                           // 4096
  float* g_Al   = g_sinv + 4096;                          // 256
  // total ~ 11.7 MB

  k_prep<<<3168, 256, 0, stream>>>(dw, ew1, dwhi, dwlo, w1hi, w1lo);
  k_enc1<<<dim3(4, 64), 256, 0, stream>>>(y, w1hi, w1lo, eb1, h);
  k_enc2z<<<1024, 128, 0, stream>>>(h, ew2, eb2, eps, z);
  k_base<<<256, 256, 0, stream>>>(z, dfw, dfb, basep);
  k_dec<<<dim3(16, 32), 256, 0, stream>>>(basep, dfw, dwhi, dwlo, db, y, lb);
  k_hmm<<<32, 256, 0, stream>>>(lb, lpi, lA, out, g_ah, g_pb, g_sinv, g_Al);
  k_xi<<<dim3(32, 127), 256, 0, stream>>>(g_ah, g_pb, g_sinv, g_Al, out);
}

// Round 4
// 338.892 us; speedup vs baseline: 2.5787x; 1.1638x over previous
//
#include <hip/hip_runtime.h>
#include <math.h>

// Problem constants (B=32, T=128, K=16, L=16); N = 4096 tokens, 784 pixels, hidden 400.
// Precision strategy: all GEMMs single-term fp16 MFMA with fp32 accumulate.
//   Error budget: per-product rel err ~2^-10; logits err ~2e-4 RMS; lb err ~3e-5;
//   HMM mixing localizes sensitivity -> output err << 2.6e-3 threshold.
// Pipeline:
//   k_prep : decw -> fp16 [896][448]; enc w1 -> fp16 [512][800]
//   k_enc1 : h[4096,400] = relu(y @ W1^T + b1)        (fp16 MFMA)
//   k_enc2z: z[4096,16]                               (fp32 VALU)
//   k_base : base_p[4096,448] = z @ Wz^T + dec_fc_b   (zero-padded h>=400)
//   k_dec  : fp16 MFMA GEMM + fused BCE -> lb[4096,16]
//   k_hmm  : scaled linear fwd/bwd (barrier-free wave-parallel) -> gamma + state
//   k_xi   : xi[32,127,16,16] fully parallel

typedef _Float16 h8v __attribute__((ext_vector_type(8)));   // MFMA A/B frag (4 VGPRs)
typedef _Float16 h4v __attribute__((ext_vector_type(4)));
typedef float f16v __attribute__((ext_vector_type(16)));    // MFMA C/D frag

// ---------------- k_prep: decw [784,400]->[896,448] f16; w1 [400,784]->[512,800] f16 ----
__global__ __launch_bounds__(256)
void k_prep(const float* __restrict__ dw, const float* __restrict__ ew1,
            _Float16* __restrict__ dwh, _Float16* __restrict__ w1h) {
  int idx = blockIdx.x * 256 + threadIdx.x;
  if (idx < 896 * 448) {
    int o = idx / 448, h2 = idx - o * 448;
    float v = (o < 784 && h2 < 400) ? dw[o * 400 + h2] : 0.f;
    dwh[idx] = (_Float16)v;
  } else if (idx < 896 * 448 + 512 * 800) {
    int j = idx - 896 * 448;
    int i = j / 800, kc = j - i * 800;
    float v = (i < 400 && kc < 784) ? ew1[i * 784 + kc] : 0.f;
    w1h[j] = (_Float16)v;
  }
}

// ---------------- K1: h = relu(y @ W1^T + b1) via fp16 MFMA ----------------
// grid (4 i-tiles of 128, 64 n-tiles of 64); block 256 = 4 waves (2n x 2i), wave 32n x 64i.
#define E1ST 40
__global__ __launch_bounds__(256, 2)
void k_enc1(const float* __restrict__ y, const _Float16* __restrict__ w1h,
            const float* __restrict__ b1, float* __restrict__ hout) {
  __shared__ __align__(16) _Float16 Ah[64 * E1ST];
  __shared__ __align__(16) _Float16 Bh[128 * E1ST];
  const int tid = threadIdx.x;
  const int i0 = blockIdx.x * 128;
  const int n0 = blockIdx.y * 64;
  const int wav = tid >> 6, lane = tid & 63;
  const int wn = wav >> 1, wi = wav & 1;
  const int ln = lane & 31, kg = lane >> 5;

  f16v acc[2];
#pragma unroll
  for (int j = 0; j < 2; ++j)
#pragma unroll
    for (int r = 0; r < 16; ++r) acc[j][r] = 0.f;

  const int ar = tid >> 3, ac4 = (tid & 7) * 4;   // A: 64 rows x 8 f4, 2/thread
  const int br = tid >> 2, bg = (tid & 3) * 8;    // B: 128 rows x 4 x8, 2/thread

#pragma unroll 1
  for (int hc = 0; hc < 25; ++hc) {
    const int h0 = hc * 32;
    __syncthreads();
#pragma unroll
    for (int it = 0; it < 2; ++it) {
      int r = ar + 32 * it;
      float4 a = make_float4(0.f, 0.f, 0.f, 0.f);
      if (h0 + ac4 < 784) a = *(const float4*)&y[(n0 + r) * 784 + h0 + ac4];
      h4v hv;
      hv[0] = (_Float16)a.x; hv[1] = (_Float16)a.y;
      hv[2] = (_Float16)a.z; hv[3] = (_Float16)a.w;
      *(h4v*)&Ah[r * E1ST + ac4] = hv;
    }
#pragma unroll
    for (int it = 0; it < 2; ++it) {
      int r = br + 64 * it;
      *(h8v*)&Bh[r * E1ST + bg] = *(const h8v*)&w1h[(i0 + r) * 800 + h0 + bg];
    }
    __syncthreads();
#pragma unroll
    for (int kk = 0; kk < 2; ++kk) {
      const int ko = kk * 16 + kg * 8;
      h8v a  = *(const h8v*)&Ah[(wn * 32 + ln) * E1ST + ko];
      h8v b0 = *(const h8v*)&Bh[(wi * 64 + ln) * E1ST + ko];
      h8v b1 = *(const h8v*)&Bh[(wi * 64 + 32 + ln) * E1ST + ko];
      acc[0] = __builtin_amdgcn_mfma_f32_32x32x16_f16(a, b0, acc[0], 0, 0, 0);
      acc[1] = __builtin_amdgcn_mfma_f32_32x32x16_f16(a, b1, acc[1], 0, 0, 0);
    }
  }
  // epilogue: C col(i) = ln, row(n) = (reg&3)+8*(reg>>2)+4*kg
#pragma unroll
  for (int j = 0; j < 2; ++j) {
    const int i = i0 + wi * 64 + j * 32 + ln;
    if (i < 400) {
      const float bias = b1[i];
#pragma unroll
      for (int reg = 0; reg < 16; ++reg) {
        const int row = n0 + wn * 32 + (reg & 3) + 8 * (reg >> 2) + 4 * kg;
        hout[row * 400 + i] = fmaxf(acc[j][reg] + bias, 0.f);
      }
    }
  }
}

// ---------------- K2: ml = h @ W2^T + b2, z = mu + eps*exp(0.5*logvar) ----------------
__global__ __launch_bounds__(128, 4)
void k_enc2z(const float* __restrict__ h, const float* __restrict__ w2,
             const float* __restrict__ b2, const float* __restrict__ eps,
             float* __restrict__ z) {
  __shared__ __align__(16) float h_lds[4 * 400];
  __shared__ __align__(16) float w2_lds[32 * 404];
  __shared__ float ml_lds[4 * 32];
  const int tid = threadIdx.x;
  const int n0 = blockIdx.x * 4;
  for (int idx = tid; idx < 400; idx += 128) {
    int r = idx / 100, c = idx % 100;
    *(float4*)&h_lds[r * 400 + c * 4] = *(const float4*)&h[(n0 + r) * 400 + c * 4];
  }
  for (int idx = tid; idx < 3200; idx += 128) {
    int r = idx / 100, c = idx % 100;
    *(float4*)&w2_lds[r * 404 + c * 4] = *(const float4*)&w2[r * 400 + c * 4];
  }
  __syncthreads();
  const int c_ = tid & 31, n_ = tid >> 5;
  float acc = 0.f;
  for (int q = 0; q < 100; ++q) {
    float4 hv = *(const float4*)&h_lds[n_ * 400 + q * 4];
    float4 wv = *(const float4*)&w2_lds[c_ * 404 + q * 4];
    acc += hv.x * wv.x + hv.y * wv.y + hv.z * wv.z + hv.w * wv.w;
  }
  ml_lds[n_ * 32 + c_] = acc + b2[c_];
  __syncthreads();
  if (tid < 64) {
    int n2 = tid >> 4, l = tid & 15;
    float mu = ml_lds[n2 * 32 + l];
    float lv = ml_lds[n2 * 32 + 16 + l];
    z[(n0 + n2) * 16 + l] = mu + eps[(n0 + n2) * 16 + l] * expf(0.5f * lv);
  }
}

// ---------------- K3: base_p = z @ Wz^T + dec_fc_b, padded [4096][448] ----------------
__global__ __launch_bounds__(256, 4)
void k_base(const float* __restrict__ z, const float* __restrict__ dfw,
            const float* __restrict__ dfb, float* __restrict__ basep) {
  __shared__ float z_lds[16 * 16];
  __shared__ __align__(16) float wz_lds[400 * 20];
  const int tid = threadIdx.x;
  const int n0 = blockIdx.x * 16;
  if (tid < 64) {
    int n = tid >> 2, c = (tid & 3) * 4;
    *(float4*)&z_lds[n * 16 + c] = *(const float4*)&z[(n0 + n) * 16 + c];
  }
  for (int idx = tid; idx < 1600; idx += 256) {
    int i = idx >> 2, c = (idx & 3) * 4;
    *(float4*)&wz_lds[i * 20 + c] = *(const float4*)&dfw[i * 32 + c];
  }
  __syncthreads();
  for (int idx = tid; idx < 7168; idx += 256) {
    int n = idx / 448, i = idx - n * 448;
    float acc = 0.f;
    if (i < 400) {
      acc = dfb[i];
#pragma unroll
      for (int q = 0; q < 4; ++q) {
        float4 zv = *(const float4*)&z_lds[n * 16 + q * 4];
        float4 wv = *(const float4*)&wz_lds[i * 20 + q * 4];
        acc += zv.x * wv.x + zv.y * wv.y + zv.z * wv.z + zv.w * wv.w;
      }
    }
    basep[(n0 + n) * 448 + i] = acc;
  }
}

// ---------------- K4: decoder GEMM fp16 MFMA + fused BCE ----------------
// grid (16 k, 32 n-tiles of 128); block 256 = 4 waves (2n x 2o), wave 64x64.
// o-tiles: 7 x 128; h-chunks: 7 x 64. A f32 register-prefetched across MFMA phase.
#define DST 72   // LDS row stride in halves (144 B, 16B-aligned, bank-rotating)
__global__ __launch_bounds__(256, 2)
void k_dec(const float* __restrict__ basep, const float* __restrict__ dfw,
           const _Float16* __restrict__ dwh, const float* __restrict__ decb,
           const float* __restrict__ y, float* __restrict__ lb) {
  __shared__ __align__(16) _Float16 Ah[128 * DST];
  __shared__ __align__(16) _Float16 Bh[128 * DST];
  __shared__ float wx[448];
  __shared__ float red[256];

  const int tid = threadIdx.x;
  const int k = blockIdx.x;
  const int n0 = blockIdx.y * 128;
  const int wav = tid >> 6, lane = tid & 63;
  const int wn = wav >> 1, wo = wav & 1;
  const int ln = lane & 31, kg = lane >> 5;

  for (int i = tid; i < 448; i += 256) wx[i] = (i < 400) ? dfw[i * 32 + 16 + k] : 0.f;

  float pr[2][16];
#pragma unroll
  for (int i = 0; i < 2; ++i)
#pragma unroll
    for (int r = 0; r < 16; ++r) pr[i][r] = 0.f;

  const int ar = tid >> 4, ac4 = (tid & 15) * 4;  // A: 128 rows x 16 f4, 8/thread
  const int br = tid >> 3, bg = (tid & 7) * 8;    // B: 128 rows x 8 x8, 4/thread
  const float* aptr = basep + (long)(n0 + ar) * 448 + ac4;

  float4 apf[8];
#pragma unroll
  for (int it = 0; it < 8; ++it) apf[it] = *(const float4*)&aptr[(16 * it) * 448];

#pragma unroll 1
  for (int ot = 0; ot < 7; ++ot) {
    const int o0 = ot * 128;
    const bool full = (ot < 6);
    f16v acc[2][2];
#pragma unroll
    for (int i = 0; i < 2; ++i)
#pragma unroll
      for (int j = 0; j < 2; ++j)
#pragma unroll
        for (int r = 0; r < 16; ++r) acc[i][j][r] = 0.f;

#pragma unroll 1
    for (int hc = 0; hc < 7; ++hc) {
      const int h0 = hc * 64;
      h8v bpf[4];
#pragma unroll
      for (int it = 0; it < 4; ++it)
        bpf[it] = *(const h8v*)&dwh[(o0 + br + 32 * it) * 448 + h0 + bg];
      __syncthreads();   // previous MFMA phase done with LDS
      {
        float4 w = *(const float4*)&wx[h0 + ac4];
#pragma unroll
        for (int it = 0; it < 8; ++it) {
          int r = ar + 16 * it;
          h4v hv;
          hv[0] = (_Float16)fmaxf(apf[it].x + w.x, 0.f);
          hv[1] = (_Float16)fmaxf(apf[it].y + w.y, 0.f);
          hv[2] = (_Float16)fmaxf(apf[it].z + w.z, 0.f);
          hv[3] = (_Float16)fmaxf(apf[it].w + w.w, 0.f);
          *(h4v*)&Ah[r * DST + ac4] = hv;
        }
      }
#pragma unroll
      for (int it = 0; it < 4; ++it)
        *(h8v*)&Bh[(br + 32 * it) * DST + bg] = bpf[it];
      __syncthreads();
      // prefetch next A chunk (in flight during MFMA)
      if (!(ot == 6 && hc == 6)) {
        const int hn = (hc == 6) ? 0 : (hc + 1) * 64;
#pragma unroll
        for (int it = 0; it < 8; ++it)
          apf[it] = *(const float4*)&aptr[(16 * it) * 448 + hn];
      }
#pragma unroll
      for (int kk = 0; kk < 4; ++kk) {
        const int ko = kk * 16 + kg * 8;
        h8v a0 = *(const h8v*)&Ah[(wn * 64 + ln) * DST + ko];
        h8v a1 = *(const h8v*)&Ah[(wn * 64 + 32 + ln) * DST + ko];
        h8v b0 = *(const h8v*)&Bh[(wo * 64 + ln) * DST + ko];
        h8v b1 = *(const h8v*)&Bh[(wo * 64 + 32 + ln) * DST + ko];
        if (full) {
          acc[0][0] = __builtin_amdgcn_mfma_f32_32x32x16_f16(a0, b0, acc[0][0], 0, 0, 0);
          acc[1][0] = __builtin_amdgcn_mfma_f32_32x32x16_f16(a1, b0, acc[1][0], 0, 0, 0);
          acc[0][1] = __builtin_amdgcn_mfma_f32_32x32x16_f16(a0, b1, acc[0][1], 0, 0, 0);
          acc[1][1] = __builtin_amdgcn_mfma_f32_32x32x16_f16(a1, b1, acc[1][1], 0, 0, 0);
        } else if (wo == 0) {
          acc[0][0] = __builtin_amdgcn_mfma_f32_32x32x16_f16(a0, b0, acc[0][0], 0, 0, 0);
          acc[1][0] = __builtin_amdgcn_mfma_f32_32x32x16_f16(a1, b0, acc[1][0], 0, 0, 0);
        }
      }
    }
    // epilogue: fused BCE. C/D: col(o) = ln, row = (reg&3)+8*(reg>>2)+4*kg
#pragma unroll
    for (int j = 0; j < 2; ++j) {
      const int o = o0 + wo * 64 + j * 32 + ln;
      const bool valid = (o < 784);
      const float bias = valid ? decb[o] : 0.f;
#pragma unroll
      for (int i = 0; i < 2; ++i) {
        if (valid) {
#pragma unroll
          for (int reg = 0; reg < 16; ++reg) {
            const int row = wn * 64 + i * 32 + (reg & 3) + 8 * (reg >> 2) + 4 * kg;
            float x = acc[i][j][reg] + bias;
            float yv = y[(n0 + row) * 784 + o];
            float spx = fmaxf(x, 0.f) + __logf(1.f + __expf(-fabsf(x)));
            float t2 = fminf(spx, 100.f);
            float t1 = fminf(spx - x, 100.f);
            pr[i][reg] += t2 + yv * (t1 - t2);
          }
        }
      }
    }
  }
#pragma unroll
  for (int i = 0; i < 2; ++i)
#pragma unroll
    for (int reg = 0; reg < 16; ++reg) {
      float v = pr[i][reg];
      v += __shfl_xor(v, 1, 64);
      v += __shfl_xor(v, 2, 64);
      v += __shfl_xor(v, 4, 64);
      v += __shfl_xor(v, 8, 64);
      v += __shfl_xor(v, 16, 64);
      if (ln == 0) {
        const int row = wn * 64 + i * 32 + (reg & 3) + 8 * (reg >> 2) + 4 * kg;
        red[wo * 128 + row] = v;
      }
    }
  __syncthreads();
  if (tid < 128) {
    float s = red[tid] + red[128 + tid];
    lb[(n0 + tid) * 16 + k] = -(s / 100.0f);
  }
}

// ---------------- K5: HMM fwd/bwd — barrier-free wave-parallel recursions ----------------
__global__ __launch_bounds__(256, 2)
void k_hmm(const float* __restrict__ lb, const float* __restrict__ lpi,
           const float* __restrict__ lA, float* __restrict__ out,
           float* __restrict__ g_ah, float* __restrict__ g_pb,
           float* __restrict__ g_sinv, float* __restrict__ g_Al) {
  __shared__ float btl[128 * 16];
  __shared__ float ah[128 * 16];
  __shared__ float bh[128 * 16];
  __shared__ float braw[128 * 16];
  __shared__ float A_l[16 * 17];
  __shared__ float pi_l[16];
  const int tid = threadIdx.x;
  const int b = blockIdx.x;

  for (int idx = tid; idx < 512; idx += 256)
    *(float4*)&btl[idx * 4] = *(const float4*)&lb[b * 2048 + idx * 4];
  if (tid < 16) {
    const int j = tid;
    float m = -1e30f;
#pragma unroll
    for (int q = 0; q < 16; ++q) m = fmaxf(m, lA[j * 16 + q]);
    float e[16]; float s = 0.f;
#pragma unroll
    for (int q = 0; q < 16; ++q) { e[q] = expf(lA[j * 16 + q] - m); s += e[q]; }
    float inv = 1.f / s;
#pragma unroll
    for (int q = 0; q < 16; ++q) {
      float v = e[q] * inv + 1e-9f;
      A_l[j * 17 + q] = v;
      g_Al[j * 16 + q] = v;
    }
  } else if (tid == 16) {
    float m = -1e30f;
#pragma unroll
    for (int q = 0; q < 16; ++q) m = fmaxf(m, lpi[q]);
    float e[16]; float s = 0.f;
#pragma unroll
    for (int q = 0; q < 16; ++q) { e[q] = expf(lpi[q] - m); s += e[q]; }
    float inv = 1.f / s;
#pragma unroll
    for (int q = 0; q < 16; ++q) pi_l[q] = e[q] * inv + 1e-9f;
  }
  __syncthreads();
  if (tid < 128) {
    const int t = tid;
    float v[16]; float m = -1e30f;
#pragma unroll
    for (int q = 0; q < 16; ++q) { v[q] = btl[t * 16 + q]; m = fmaxf(m, v[q]); }
#pragma unroll
    for (int q = 0; q < 16; ++q) btl[t * 16 + q] = expf(v[q] - m);
  }
  __syncthreads();
  const int lane = tid & 63;
  const int kk = lane & 15, grp = lane >> 4;
  // fwd recursion: wave 0 only; bwd: wave 1 only. Disjoint LDS — no block barriers.
  if (tid < 64) {
    float v0 = pi_l[kk] * btl[kk];
    float ss0 = v0;
    ss0 += __shfl_xor(ss0, 1, 64); ss0 += __shfl_xor(ss0, 2, 64);
    ss0 += __shfl_xor(ss0, 4, 64); ss0 += __shfl_xor(ss0, 8, 64);
    if (grp == 0) ah[kk] = v0 / ss0;
    for (int t = 1; t < 128; ++t) {
      float acc = 0.f;
#pragma unroll
      for (int jj = 0; jj < 4; ++jj) {
        int j = grp * 4 + jj;
        acc = fmaf(ah[(t - 1) * 16 + j], A_l[j * 17 + kk], acc);
      }
      acc += __shfl_xor(acc, 16, 64);
      acc += __shfl_xor(acc, 32, 64);
      float v = acc * btl[t * 16 + kk];
      float ss = v;
      ss += __shfl_xor(ss, 1, 64); ss += __shfl_xor(ss, 2, 64);
      ss += __shfl_xor(ss, 4, 64); ss += __shfl_xor(ss, 8, 64);
      if (grp == 0) ah[t * 16 + kk] = v / ss;
    }
  } else if (tid < 128) {
    if (grp == 0) bh[127 * 16 + kk] = 1.f;
    for (int t = 126; t >= 0; --t) {
      float acc = 0.f;
#pragma unroll
      for (int q = 0; q < 4; ++q) {
        int k2 = grp * 4 + q;
        acc = fmaf(A_l[kk * 17 + k2], btl[(t + 1) * 16 + k2] * bh[(t + 1) * 16 + k2], acc);
      }
      acc += __shfl_xor(acc, 16, 64);
      acc += __shfl_xor(acc, 32, 64);
      float ss = acc;
      ss += __shfl_xor(ss, 1, 64); ss += __shfl_xor(ss, 2, 64);
      ss += __shfl_xor(ss, 4, 64); ss += __shfl_xor(ss, 8, 64);
      if (grp == 0) { braw[t * 16 + kk] = acc; bh[t * 16 + kk] = acc / ss; }
    }
  }
  __syncthreads();
  if (tid < 128) {
    const int t = tid;
    float g[16]; float s2 = 0.f;
#pragma unroll
    for (int q = 0; q < 16; ++q) { g[q] = ah[t * 16 + q] * bh[t * 16 + q]; s2 += g[q]; }
    float inv = 1.f / s2;
#pragma unroll
    for (int c = 0; c < 4; ++c) {
      float4 o;
      o.x = g[c * 4 + 0] * inv; o.y = g[c * 4 + 1] * inv;
      o.z = g[c * 4 + 2] * inv; o.w = g[c * 4 + 3] * inv;
      *(float4*)&out[(b * 128 + t) * 16 + c * 4] = o;
      float4 av = *(float4*)&ah[t * 16 + c * 4];
      *(float4*)&g_ah[(b * 128 + t) * 16 + c * 4] = av;
      float4 p;
      p.x = btl[t * 16 + c * 4 + 0] * bh[t * 16 + c * 4 + 0];
      p.y = btl[t * 16 + c * 4 + 1] * bh[t * 16 + c * 4 + 1];
      p.z = btl[t * 16 + c * 4 + 2] * bh[t * 16 + c * 4 + 2];
      p.w = btl[t * 16 + c * 4 + 3] * bh[t * 16 + c * 4 + 3];
      *(float4*)&g_pb[(b * 128 + t) * 16 + c * 4] = p;
    }
  } else {
    const int t = tid - 128;
    if (t < 127) {
      float s2 = 0.f;
#pragma unroll
      for (int q = 0; q < 16; ++q) s2 += ah[t * 16 + q] * braw[t * 16 + q];
      g_sinv[b * 128 + t] = 1.f / s2;
    }
  }
}

// ---------------- K6: xi[b,t,j,k] fully parallel ----------------
__global__ __launch_bounds__(256)
void k_xi(const float* __restrict__ g_ah, const float* __restrict__ g_pb,
          const float* __restrict__ g_sinv, const float* __restrict__ g_Al,
          float* __restrict__ out) {
  const int b = blockIdx.x, t = blockIdx.y;
  const int tid = threadIdx.x;
  const int j = tid >> 4, k2 = tid & 15;
  float val = g_ah[(b * 128 + t) * 16 + j] * g_Al[j * 16 + k2] *
              g_pb[(b * 128 + t + 1) * 16 + k2] * g_sinv[b * 128 + t];
  out[65536 + (b * 127 + t) * 256 + tid] = val;
}

extern "C" void kernel_launch(void* const* d_in, const int* in_sizes, int n_in,
                              void* d_out, int out_size, void* d_ws, size_t ws_size,
                              hipStream_t stream) {
  (void)in_sizes; (void)n_in; (void)out_size; (void)ws_size;
  const float* y   = (const float*)d_in[0];   // (4096,784)
  const float* ew1 = (const float*)d_in[1];   // (400,784)
  const float* eb1 = (const float*)d_in[2];   // (400,)
  const float* ew2 = (const float*)d_in[3];   // (32,400)
  const float* eb2 = (const float*)d_in[4];   // (32,)
  const float* dfw = (const float*)d_in[5];   // (400,32)
  const float* dfb = (const float*)d_in[6];   // (400,)
  const float* dw  = (const float*)d_in[7];   // (784,400)
  const float* db  = (const float*)d_in[8];   // (784,)
  const float* lpi = (const float*)d_in[9];   // (16,)
  const float* lA  = (const float*)d_in[10];  // (16,16)
  const float* eps = (const float*)d_in[11];  // (4096,16)
  float* out = (float*)d_out;

  float* ws = (float*)d_ws;
  float* h      = ws;                 // then reused as basep
  float* basep  = ws;
  float* z      = ws + 1835008;
  float* lb     = z + 65536;
  _Float16* dwh = (_Float16*)(lb + 65536);    // 896*448
  _Float16* w1h = dwh + 896 * 448;            // 512*800
  float* g_ah   = (float*)(w1h + 512 * 800);  // 65536
  float* g_pb   = g_ah + 65536;
  float* g_sinv = g_pb + 65536;               // 4096
  float* g_Al   = g_sinv + 4096;              // 256

  k_prep<<<3168, 256, 0, stream>>>(dw, ew1, dwh, w1h);
  k_enc1<<<dim3(4, 64), 256, 0, stream>>>(y, w1h, eb1, h);
  k_enc2z<<<1024, 128, 0, stream>>>(h, ew2, eb2, eps, z);
  k_base<<<256, 256, 0, stream>>>(z, dfw, dfb, basep);
  k_dec<<<dim3(16, 32), 256, 0, stream>>>(basep, dfw, dwh, db, y, lb);
  k_hmm<<<32, 256, 0, stream>>>(lb, lpi, lA, out, g_ah, g_pb, g_sinv, g_Al);
  k_xi<<<dim3(32, 127), 256, 0, stream>>>(g_ah, g_pb, g_sinv, g_Al, out);
}